// Round 2
// baseline (1512.451 us; speedup 1.0000x reference)
//
#include <hip/hip_runtime.h>
#include <hip/hip_bf16.h>

// ---------- types ----------
typedef __attribute__((ext_vector_type(8))) short bf16x8;   // 8 bf16 in 4 VGPRs (guide §3)
typedef __attribute__((ext_vector_type(4))) float f32x4;
typedef __attribute__((ext_vector_type(8))) unsigned short u16x8;
typedef unsigned short u16;

#define AS1(p) ((__attribute__((address_space(1))) void*)(p))
#define AS3(p) ((__attribute__((address_space(3))) void*)(p))
// async global->LDS, 16B per lane, LDS dest = wave-uniform base + lane*16
#define GLL16(g, l) __builtin_amdgcn_global_load_lds(AS1(g), AS3(l), 16, 0, 0)

__device__ __forceinline__ u16 f2bf(float x) {
  return __builtin_bit_cast(u16, __float2bfloat16(x));
}
__device__ __forceinline__ float bf2f(u16 u) {
  return __builtin_bit_cast(float, ((unsigned)u) << 16);
}
__device__ __forceinline__ float rdlane(float v, int l) {
  return __builtin_bit_cast(float, __builtin_amdgcn_readlane(__builtin_bit_cast(int, v), l));
}
__device__ __forceinline__ float wsum(float v) {  // 64-lane sum, result in all lanes
  v += __shfl_xor(v, 1, 64);
  v += __shfl_xor(v, 2, 64);
  v += __shfl_xor(v, 4, 64);
  v += __shfl_xor(v, 8, 64);
  v += __shfl_xor(v, 16, 64);
  v += __shfl_xor(v, 32, 64);
  return v;
}
__device__ __forceinline__ f32x4 mfma16(bf16x8 a, bf16x8 b, f32x4 c) {
  return __builtin_amdgcn_mfma_f32_16x16x32_bf16(a, b, c, 0, 0, 0);
}

// ---------- convert hs f32 -> bf16 (8 elems/thread) ----------
__global__ __launch_bounds__(256) void conv_bf16(const float* __restrict__ in,
                                                 u16* __restrict__ out) {
  size_t g = (size_t)blockIdx.x * 256 + threadIdx.x;
  const float4* p = reinterpret_cast<const float4*>(in) + g * 2;
  float4 a = p[0], b = p[1];
  u16x8 r;
  r[0] = f2bf(a.x); r[1] = f2bf(a.y); r[2] = f2bf(a.z); r[3] = f2bf(a.w);
  r[4] = f2bf(b.x); r[5] = f2bf(b.y); r[6] = f2bf(b.z); r[7] = f2bf(b.w);
  *reinterpret_cast<u16x8*>(out + g * 8) = r;
}

// ---------- transpose + convert: W[K][N] f32 -> Wt[N][K] bf16 ----------
__global__ __launch_bounds__(256) void wt_conv(const float* __restrict__ W,
                                               u16* __restrict__ Wt, int Kd, int N) {
  __shared__ float t[64][65];
  const int n0 = blockIdx.x * 64, k0 = blockIdx.y * 64;
  const int tx = threadIdx.x & 63, ty = threadIdx.x >> 6;
#pragma unroll
  for (int rr = 0; rr < 16; ++rr) {
    int r = rr * 4 + ty;
    t[r][tx] = W[(size_t)(k0 + r) * N + n0 + tx];
  }
  __syncthreads();
#pragma unroll
  for (int rr = 0; rr < 16; ++rr) {
    int r = rr * 4 + ty;
    Wt[(size_t)(n0 + r) * Kd + k0 + tx] = f2bf(t[tx][r]);
  }
}

// ---------- ilr_w strip into WcatT rows [6144,6272) ----------
__global__ __launch_bounds__(256) void ilr_strip(const float* __restrict__ ilr_w,
                                                 u16* __restrict__ WcatT) {
  int g = blockIdx.x * 256 + threadIdx.x;  // 128*2048
  int p = g >> 11, k = g & 2047;
  float v = (p < 32) ? ilr_w[k * 32 + p] : 0.f;
  WcatT[(size_t)(6144 + p) * 2048 + k] = f2bf(v);
}

// ---------- staging: 128x32 bf16 tile per matrix, 2 rounds of 256x16B ----------
__device__ __forceinline__ void stage_pair(const u16* __restrict__ A, const u16* __restrict__ Bt,
                                           u16* As, u16* Bs, int Kd, int mT, int nT, int kt,
                                           int tid) {
#pragma unroll
  for (int r = 0; r < 2; ++r) {
    int e = r * 2048 + tid * 8;
    int row = e >> 5, kk = e & 31;
    GLL16(A + (size_t)(mT + row) * Kd + kt + kk, As + e);
    GLL16(Bt + (size_t)(nT + row) * Kd + kt + kk, Bs + e);
  }
}

// ---------- MFMA GEMM  C[M][N] = A[M][Kd] * Bt[N][Kd]^T ----------
// MODE 0: proj epilogue -> XC/XB/XA bf16 in (B,NH,L,HD) + coeff f32 (cols>=6144)
// MODE 1: plain f32 output C[M][N]
template <int MODE>
__global__ __launch_bounds__(256) void gemm_bt(const u16* __restrict__ A,
                                               const u16* __restrict__ Bt, int M, int N, int Kd,
                                               u16* __restrict__ O0, u16* __restrict__ O1,
                                               u16* __restrict__ O2,
                                               float* __restrict__ coeffOut,
                                               const float* __restrict__ ilrb,
                                               float* __restrict__ Cout) {
  __shared__ __align__(16) u16 As[2][4096];
  __shared__ __align__(16) u16 Bs[2][4096];
  const int tid = threadIdx.x;
  const int lane = tid & 63;
  const int wid = tid >> 6;
  const int wr = wid >> 1, wc = wid & 1;
  const int l15 = lane & 15, l4 = lane >> 4;
  const int mT = blockIdx.y << 7, nT = blockIdx.x << 7;

  f32x4 acc[4][4];
#pragma unroll
  for (int m = 0; m < 4; ++m)
#pragma unroll
    for (int n = 0; n < 4; ++n) acc[m][n] = (f32x4){0.f, 0.f, 0.f, 0.f};

  stage_pair(A, Bt, &As[0][0], &Bs[0][0], Kd, mT, nT, 0, tid);
  const int nIter = Kd >> 5;
  const int aoff = (wr * 64 + l15) * 32 + l4 * 8;
  const int boff = (wc * 64 + l15) * 32 + l4 * 8;
#pragma unroll 1
  for (int it = 0; it < nIter; ++it) {
    const int cur = it & 1;
    __syncthreads();  // buf 'cur' DMA drained for all waves; prev reads done
    if (it + 1 < nIter)
      stage_pair(A, Bt, &As[cur ^ 1][0], &Bs[cur ^ 1][0], Kd, mT, nT, (it + 1) << 5, tid);
    bf16x8 av[4], bv[4];
#pragma unroll
    for (int x = 0; x < 4; ++x) {
      av[x] = *reinterpret_cast<const bf16x8*>(&As[cur][aoff + x * 512]);
      bv[x] = *reinterpret_cast<const bf16x8*>(&Bs[cur][boff + x * 512]);
    }
#pragma unroll
    for (int m = 0; m < 4; ++m)
#pragma unroll
      for (int n = 0; n < 4; ++n) acc[m][n] = mfma16(av[m], bv[n], acc[m][n]);
  }
  // epilogue: C/D layout col=lane&15, row=(lane>>4)*4+e (m89-verified)
#pragma unroll
  for (int m = 0; m < 4; ++m) {
#pragma unroll
    for (int n = 0; n < 4; ++n) {
      const int col = nT + wc * 64 + n * 16 + l15;
#pragma unroll
      for (int e = 0; e < 4; ++e) {
        const int row = mT + wr * 64 + m * 16 + l4 * 4 + e;
        float v = acc[m][n][e];
        if constexpr (MODE == 1) {
          Cout[(size_t)row * N + col] = v;
        } else {
          const int bb = row >> 11, lt = row & 2047;
          if (col < 6144) {
            const int mat = col >> 11;  // block-uniform (tile=128 cols | 2048 boundary)
            u16* base = (mat == 0) ? O0 : ((mat == 1) ? O1 : O2);
            const int hh = (col >> 6) & 31, dd = col & 63;
            base[(((size_t)(bb * 32 + hh)) * 2048 + lt) * 64 + dd] = f2bf(v);
          } else {
            const int h3 = col - 6144;
            if (h3 < 32) {
              const float x = v + ilrb[h3];
              const float sig = 1.f / (1.f + expf(-x));
              const int tok = lt & 15;
              coeffOut[((size_t)(bb * 32 + h3)) * 2048 + lt] =
                  sig * (1.f / (64.f * (float)(tok + 1)));
            }
          }
        }
      }
    }
  }
  (void)M;
}

// ---------- sequential TTT scan: one block per (b,h), f32 state ----------
// lane j = feature col (HD=64=wave). wave wq owns rows {wq,wq+4,wq+8,wq+12} and
// k-slice [16wq,16wq+16) of W1 (W1q regs, column j).
__global__ __launch_bounds__(256) void ttt_scan(
    const u16* __restrict__ XC, const u16* __restrict__ XB, const u16* __restrict__ XA,
    const float* __restrict__ coeff, const float* __restrict__ lnw_g,
    const float* __restrict__ lnb_g, const float* __restrict__ W1g,
    const float* __restrict__ b1g, u16* __restrict__ XCW) {
  const int bh = blockIdx.x;
  const int b = bh >> 5, h = bh & 31;
  const int j = threadIdx.x & 63;
  const int wq = threadIdx.x >> 6;
  const int wqu = __builtin_amdgcn_readfirstlane(wq);
  const int kb = wqu * 16;

  const u16* xcb = XC + (size_t)bh * (2048 * 64);
  const u16* xbb = XB + (size_t)bh * (2048 * 64);
  const u16* xab = XA + (size_t)bh * (2048 * 64);
  const float* cob = coeff + (size_t)bh * 2048;

  const float lnw = lnw_g[h * 64 + j];
  const float lnb = lnb_g[h * 64 + j];
  float W1q[16];
#pragma unroll
  for (int kk = 0; kk < 16; ++kk) W1q[kk] = W1g[(size_t)h * 4096 + (kb + kk) * 64 + j];
  float b1c = b1g[h * 64 + j];

  __shared__ __align__(16) float xb_s[16 * 64];
  __shared__ __align__(16) float xc_s[16 * 64];
  __shared__ float Zp[4][16][64];
  __shared__ float grad_s[16][64];

  const int r15 = j & 15, q4 = j >> 4;

#pragma unroll 1
  for (int c = 0; c < 128; ++c) {
    const u16* xbc = xbb + c * 1024;
    const u16* xcc = xcb + c * 1024;
    const u16* xac = xab + c * 1024;
    // stage: bf16 -> f32 LDS tiles (8B/thread/tile, coalesced)
    {
      const int e = threadIdx.x * 4;
      ushort4 vb = *reinterpret_cast<const ushort4*>(xbc + e);
      ushort4 vc = *reinterpret_cast<const ushort4*>(xcc + e);
      float4 fb = {bf2f(vb.x), bf2f(vb.y), bf2f(vb.z), bf2f(vb.w)};
      float4 fc = {bf2f(vc.x), bf2f(vc.y), bf2f(vc.z), bf2f(vc.w)};
      *reinterpret_cast<float4*>(xb_s + e) = fb;
      *reinterpret_cast<float4*>(xc_s + e) = fc;
    }
    float xa_own[4], co_own[4];
#pragma unroll
    for (int rr = 0; rr < 4; ++rr) {
      const int i = wq + 4 * rr;
      xa_own[rr] = bf2f(xac[i * 64 + j]);
      co_own[rr] = cob[c * 16 + i];
    }
    const float co15 = cob[c * 16 + 15];
    __syncthreads();  // bar0: tiles staged

    // B: Z1 partials (k-slice per wave), uniform LDS reads -> broadcast
#pragma unroll
    for (int i = 0; i < 16; ++i) {
      float acc = 0.f;
#pragma unroll
      for (int kk = 0; kk < 16; ++kk) acc = fmaf(xb_s[i * 64 + kb + kk], W1q[kk], acc);
      Zp[wqu][i][j] = acc;
    }
    __syncthreads();  // bar1

    // C: LN-L2 backward on owned rows -> grad
#pragma unroll
    for (int rr = 0; rr < 4; ++rr) {
      const int i = wq + 4 * rr;
      const float xb_own = xb_s[i * 64 + j];
      float z = b1c + Zp[0][i][j] + Zp[1][i][j] + Zp[2][i][j] + Zp[3][i][j];
      const float mu = wsum(z) * 0.015625f;
      const float d = z - mu;
      const float var = wsum(d * d) * 0.015625f;
      const float rstd = rsqrtf(var + 1e-6f);
      const float xhat = d * rstd;
      const float y = fmaf(lnw, xhat, lnb);
      const float g = (y - (xa_own[rr] - xb_own)) * lnw;
      const float gs = wsum(g);
      const float gx = wsum(g * xhat);
      grad_s[i][j] = (64.f * g - gs - xhat * gx) * (rstd * 0.015625f);
    }
    __syncthreads();  // bar2

    float gcol[16];
#pragma unroll
    for (int r = 0; r < 16; ++r) gcol[r] = grad_s[r][j];

    // E: xc@W1 partials (Zp reuse; all C-phase Zp reads were before bar2)
#pragma unroll
    for (int i = 0; i < 16; ++i) {
      float acc = 0.f;
#pragma unroll
      for (int kk = 0; kk < 16; ++kk) acc = fmaf(xc_s[i * 64 + kb + kk], W1q[kk], acc);
      Zp[wqu][i][j] = acc;
    }
    __syncthreads();  // bar3

    // hoisted xb values for P (lane r15 reads row r15, rotated-k: 2-way conflict = free)
    float xbv[16];
#pragma unroll
    for (int kk = 0; kk < 16; ++kk) {
      const int k = (q4 << 4) + ((kk + r15) & 15);
      xbv[kk] = xb_s[r15 * 64 + k];
    }

    // F: per owned row: P row (tril(xc@xb^T)), D2=P@grad, Z1_bar, LN fwd, out
#pragma unroll
    for (int rr = 0; rr < 4; ++rr) {
      const int i = wq + 4 * rr;
      const float xcw = Zp[0][i][j] + Zp[1][i][j] + Zp[2][i][j] + Zp[3][i][j];
      float pa = 0.f;
#pragma unroll
      for (int kk = 0; kk < 16; ++kk) {
        const int k = (q4 << 4) + ((kk + r15) & 15);
        pa = fmaf(xc_s[i * 64 + k], xbv[kk], pa);
      }
      pa += __shfl_xor(pa, 16, 64);
      pa += __shfl_xor(pa, 32, 64);
      const float Pm = (r15 <= i) ? pa : 0.f;  // tril mask (incl diag)
      float d2 = 0.f, pfi = 0.f;
#pragma unroll
      for (int r = 0; r < 16; ++r) {
        const float sP = rdlane(Pm, r);
        d2 = fmaf(sP, gcol[r], d2);
        pfi += (r <= i) ? gcol[r] : 0.f;  // inclusive prefix of grad rows
      }
      const float b1bar = fmaf(-co_own[rr], pfi, b1c);
      const float zb = fmaf(-co_own[rr], d2, xcw) + b1bar;
      const float mu2 = wsum(zb) * 0.015625f;
      const float dd = zb - mu2;
      const float var2 = wsum(dd * dd) * 0.015625f;
      const float rstd2 = rsqrtf(var2 + 1e-6f);
      const float o = xc_s[i * 64 + j] + fmaf(lnw, dd * rstd2, lnb);
      XCW[((size_t)(b * 2048 + c * 16 + i)) * 2048 + h * 64 + j] = f2bf(o);
    }

    // W1/b1 update (entering grad; xc@W1 already computed in E)
    {
      float tr[16];
#pragma unroll
      for (int r = 0; r < 16; ++r) tr[r] = -co15 * gcol[r];
#pragma unroll
      for (int r = 0; r < 16; ++r) {
#pragma unroll
        for (int kk = 0; kk < 16; ++kk)
          W1q[kk] = fmaf(xb_s[r * 64 + kb + kk], tr[r], W1q[kk]);
      }
      float pf15 = 0.f;
#pragma unroll
      for (int r = 0; r < 16; ++r) pf15 += gcol[r];
      b1c = fmaf(-co15, pf15, b1c);
    }
    __syncthreads();  // bar4: protects xb_s/xc_s/Zp reuse next chunk
  }
}

// ---------- launcher ----------
extern "C" void kernel_launch(void* const* d_in, const int* in_sizes, int n_in, void* d_out,
                              int out_size, void* d_ws, size_t ws_size, hipStream_t stream) {
  const float* hs = (const float*)d_in[0];
  const float* Wq = (const float*)d_in[1];
  const float* Wk = (const float*)d_in[2];
  const float* Wv = (const float*)d_in[3];
  const float* Wo = (const float*)d_in[4];
  const float* ilr_w = (const float*)d_in[5];
  const float* ilr_b = (const float*)d_in[6];
  const float* lnw = (const float*)d_in[7];
  const float* lnb = (const float*)d_in[8];
  const float* W1 = (const float*)d_in[9];
  const float* b1 = (const float*)d_in[10];
  float* out = (float*)d_out;

  // ws layout (93,847,552 B total). Guard: if ws too small, return zeros-output
  // (clean absmax~6 failure instead of a device fault) -> diagnoses ws_size.
  if (ws_size < 93847552u) return;
  char* ws = (char*)d_ws;
  u16* hsb = (u16*)(ws + 0);                 // 33,554,432 B; reused as XCW after gemm<0>
  u16* WcatT = (u16*)(ws + 33554432);        // 25,690,112 B; reused as WoT after gemm<0>
  u16* XCbf = (u16*)(ws + 59244544);         // 33,554,432 B
  float* coeffb = (float*)(ws + 92798976);   //  1,048,576 B
  u16* XCW = hsb;
  u16* WoT = (u16*)(ws + 33554432);
  // d_out doubles as scratch for XB/XA (dead before gemm<1> overwrites all of d_out)
  u16* XBbf = (u16*)d_out;                         // 33,554,432 B
  u16* XAbf = (u16*)((char*)d_out + 33554432);     // 33,554,432 B (= 67,108,864 total = out bytes)

  conv_bf16<<<8192, 256, 0, stream>>>(hs, hsb);
  wt_conv<<<dim3(32, 32), 256, 0, stream>>>(Wq, WcatT, 2048, 2048);
  wt_conv<<<dim3(32, 32), 256, 0, stream>>>(Wk, WcatT + (size_t)2048 * 2048, 2048, 2048);
  wt_conv<<<dim3(32, 32), 256, 0, stream>>>(Wv, WcatT + (size_t)4096 * 2048, 2048, 2048);
  ilr_strip<<<1024, 256, 0, stream>>>(ilr_w, WcatT);

  gemm_bt<0><<<dim3(49, 64), 256, 0, stream>>>(hsb, WcatT, 8192, 6272, 2048, XCbf, XBbf, XAbf,
                                               coeffb, ilr_b, nullptr);
  // Wo transpose AFTER gemm<0> (WoT overwrites WcatT region, stream-ordered WAR)
  wt_conv<<<dim3(32, 32), 256, 0, stream>>>(Wo, WoT, 2048, 2048);
  // scan writes XCW over hsb region (hsb dead after gemm<0>)
  ttt_scan<<<128, 256, 0, stream>>>(XCbf, XBbf, XAbf, coeffb, lnw, lnb, W1, b1, XCW);
  gemm_bt<1><<<dim3(16, 64), 256, 0, stream>>>(XCW, WoT, 8192, 2048, 2048, nullptr, nullptr,
                                               nullptr, nullptr, nullptr, out);

  (void)in_sizes; (void)n_in; (void)out_size;
}

// Round 3
// 975.045 us; speedup vs baseline: 1.5512x; 1.5512x over previous
//
#include <hip/hip_runtime.h>
#include <hip/hip_bf16.h>

// ---------- types ----------
typedef __attribute__((ext_vector_type(8))) short bf16x8;   // 8 bf16 in 4 VGPRs
typedef __attribute__((ext_vector_type(4))) float f32x4;
typedef __attribute__((ext_vector_type(8))) unsigned short u16x8;
typedef unsigned short u16;

#define AS1(p) ((__attribute__((address_space(1))) void*)(p))
#define AS3(p) ((__attribute__((address_space(3))) void*)(p))
#define GLL16(g, l) __builtin_amdgcn_global_load_lds(AS1(g), AS3(l), 16, 0, 0)

__device__ __forceinline__ u16 f2bf(float x) {
  return __builtin_bit_cast(u16, __float2bfloat16(x));
}
__device__ __forceinline__ float bf2f(u16 u) {
  return __builtin_bit_cast(float, ((unsigned)u) << 16);
}
__device__ __forceinline__ f32x4 mfma16(bf16x8 a, bf16x8 b, f32x4 c) {
  return __builtin_amdgcn_mfma_f32_16x16x32_bf16(a, b, c, 0, 0, 0);
}
// butterfly sum over the 16-lane (l15) groups, two stat arrays at once
__device__ __forceinline__ void bfly16(float* a, float* bq) {
#pragma unroll
  for (int m = 1; m <= 8; m <<= 1) {
#pragma unroll
    for (int e = 0; e < 4; ++e) {
      a[e] += __shfl_xor(a[e], m, 64);
      bq[e] += __shfl_xor(bq[e], m, 64);
    }
  }
}
// swizzled bf16 element read from a [16][64] tile (byte ^= (row&7)<<4)
__device__ __forceinline__ float ld16s(const u16* base, int row, int colp) {
  const int byi = row * 128 + ((colp * 2) ^ ((row & 7) << 4));
  return bf2f(*(const u16*)((const char*)base + byi));
}

// ---------- convert hs f32 -> bf16 (8 elems/thread) ----------
__global__ __launch_bounds__(256) void conv_bf16(const float* __restrict__ in,
                                                 u16* __restrict__ out) {
  size_t g = (size_t)blockIdx.x * 256 + threadIdx.x;
  const float4* p = reinterpret_cast<const float4*>(in) + g * 2;
  float4 a = p[0], b = p[1];
  u16x8 r;
  r[0] = f2bf(a.x); r[1] = f2bf(a.y); r[2] = f2bf(a.z); r[3] = f2bf(a.w);
  r[4] = f2bf(b.x); r[5] = f2bf(b.y); r[6] = f2bf(b.z); r[7] = f2bf(b.w);
  *reinterpret_cast<u16x8*>(out + g * 8) = r;
}

// ---------- transpose + convert: W[K][N] f32 -> Wt[N][K] bf16 ----------
__global__ __launch_bounds__(256) void wt_conv(const float* __restrict__ W,
                                               u16* __restrict__ Wt, int Kd, int N) {
  __shared__ float t[64][65];
  const int n0 = blockIdx.x * 64, k0 = blockIdx.y * 64;
  const int tx = threadIdx.x & 63, ty = threadIdx.x >> 6;
#pragma unroll
  for (int rr = 0; rr < 16; ++rr) {
    int r = rr * 4 + ty;
    t[r][tx] = W[(size_t)(k0 + r) * N + n0 + tx];
  }
  __syncthreads();
#pragma unroll
  for (int rr = 0; rr < 16; ++rr) {
    int r = rr * 4 + ty;
    Wt[(size_t)(n0 + r) * Kd + k0 + tx] = f2bf(t[tx][r]);
  }
}

// ---------- ilr_w strip into WcatT rows [6144,6272) ----------
__global__ __launch_bounds__(256) void ilr_strip(const float* __restrict__ ilr_w,
                                                 u16* __restrict__ WcatT) {
  int g = blockIdx.x * 256 + threadIdx.x;  // 128*2048
  int p = g >> 11, k = g & 2047;
  float v = (p < 32) ? ilr_w[k * 32 + p] : 0.f;
  WcatT[(size_t)(6144 + p) * 2048 + k] = f2bf(v);
}

// ---------- staging: 128x32 bf16 tile per matrix ----------
__device__ __forceinline__ void stage_pair(const u16* __restrict__ A, const u16* __restrict__ Bt,
                                           u16* As, u16* Bs, int Kd, int mT, int nT, int kt,
                                           int tid) {
#pragma unroll
  for (int r = 0; r < 2; ++r) {
    int e = r * 2048 + tid * 8;
    int row = e >> 5, kk = e & 31;
    GLL16(A + (size_t)(mT + row) * Kd + kt + kk, As + e);
    GLL16(Bt + (size_t)(nT + row) * Kd + kt + kk, Bs + e);
  }
}

// ---------- MFMA GEMM  C[M][N] = A[M][Kd] * Bt[N][Kd]^T ----------
template <int MODE>
__global__ __launch_bounds__(256) void gemm_bt(const u16* __restrict__ A,
                                               const u16* __restrict__ Bt, int M, int N, int Kd,
                                               u16* __restrict__ O0, u16* __restrict__ O1,
                                               u16* __restrict__ O2,
                                               float* __restrict__ coeffOut,
                                               const float* __restrict__ ilrb,
                                               float* __restrict__ Cout) {
  __shared__ __align__(16) u16 As[2][4096];
  __shared__ __align__(16) u16 Bs[2][4096];
  const int tid = threadIdx.x;
  const int lane = tid & 63;
  const int wid = tid >> 6;
  const int wr = wid >> 1, wc = wid & 1;
  const int l15 = lane & 15, l4 = lane >> 4;
  const int mT = blockIdx.y << 7, nT = blockIdx.x << 7;

  f32x4 acc[4][4];
#pragma unroll
  for (int m = 0; m < 4; ++m)
#pragma unroll
    for (int n = 0; n < 4; ++n) acc[m][n] = (f32x4){0.f, 0.f, 0.f, 0.f};

  stage_pair(A, Bt, &As[0][0], &Bs[0][0], Kd, mT, nT, 0, tid);
  const int nIter = Kd >> 5;
  const int aoff = (wr * 64 + l15) * 32 + l4 * 8;
  const int boff = (wc * 64 + l15) * 32 + l4 * 8;
#pragma unroll 1
  for (int it = 0; it < nIter; ++it) {
    const int cur = it & 1;
    __syncthreads();
    if (it + 1 < nIter)
      stage_pair(A, Bt, &As[cur ^ 1][0], &Bs[cur ^ 1][0], Kd, mT, nT, (it + 1) << 5, tid);
    bf16x8 av[4], bv[4];
#pragma unroll
    for (int x = 0; x < 4; ++x) {
      av[x] = *reinterpret_cast<const bf16x8*>(&As[cur][aoff + x * 512]);
      bv[x] = *reinterpret_cast<const bf16x8*>(&Bs[cur][boff + x * 512]);
    }
#pragma unroll
    for (int m = 0; m < 4; ++m)
#pragma unroll
      for (int n = 0; n < 4; ++n) acc[m][n] = mfma16(av[m], bv[n], acc[m][n]);
  }
#pragma unroll
  for (int m = 0; m < 4; ++m) {
#pragma unroll
    for (int n = 0; n < 4; ++n) {
      const int col = nT + wc * 64 + n * 16 + l15;
#pragma unroll
      for (int e = 0; e < 4; ++e) {
        const int row = mT + wr * 64 + m * 16 + l4 * 4 + e;
        float v = acc[m][n][e];
        if constexpr (MODE == 1) {
          Cout[(size_t)row * N + col] = v;
        } else {
          const int bb = row >> 11, lt = row & 2047;
          if (col < 6144) {
            const int mat = col >> 11;
            u16* base = (mat == 0) ? O0 : ((mat == 1) ? O1 : O2);
            const int hh = (col >> 6) & 31, dd = col & 63;
            base[(((size_t)(bb * 32 + hh)) * 2048 + lt) * 64 + dd] = f2bf(v);
          } else {
            const int h3 = col - 6144;
            if (h3 < 32) {
              const float x = v + ilrb[h3];
              const float sig = 1.f / (1.f + expf(-x));
              const int tok = lt & 15;
              coeffOut[((size_t)(bb * 32 + h3)) * 2048 + lt] =
                  sig * (1.f / (64.f * (float)(tok + 1)));
            }
          }
        }
      }
    }
  }
  (void)M;
}

// ---------- MFMA-based sequential TTT scan: one block (4 waves) per (b,h) ----------
// Wave wq owns output cols [16wq,16wq+16). Lane: col = wq*16 + (lane&15), l4 = lane>>4.
// W1 master f32 held in B-frag layout: w1m[s][e] = W1[k=s*32+l4*8+e][col].
// MFMA C layout (verified R2): lane holds rows i=l4*4+e, col=l15 of each 16x16 tile.
__global__ __launch_bounds__(256) void ttt_scan(
    const u16* __restrict__ XC, const u16* __restrict__ XB, const u16* __restrict__ XA,
    const float* __restrict__ coeff, const float* __restrict__ lnw_g,
    const float* __restrict__ lnb_g, const float* __restrict__ W1g,
    const float* __restrict__ b1g, u16* __restrict__ XCW) {
  const int bh = blockIdx.x;
  const int b = bh >> 5, h = bh & 31;
  const int tid = threadIdx.x;
  const int lane = tid & 63;
  const int wq = tid >> 6;
  const int l15 = lane & 15, l4 = lane >> 4;
  const int col = wq * 16 + l15;

  const u16* xbb = XB + (size_t)bh * 131072;
  const u16* xcb = XC + (size_t)bh * 131072;
  const u16* xab = XA + (size_t)bh * 131072;
  const float* cob = coeff + (size_t)bh * 2048;

  const float lnw_c = lnw_g[h * 64 + col];
  const float lnb_c = lnb_g[h * 64 + col];
  float b1c = b1g[h * 64 + col];
  float w1m[2][8];
#pragma unroll
  for (int s = 0; s < 2; ++s)
#pragma unroll
    for (int e = 0; e < 8; ++e)
      w1m[s][e] = W1g[(size_t)h * 4096 + (s * 32 + l4 * 8 + e) * 64 + col];

  __shared__ __align__(16) u16 xb_t[2][1024];   // [16][64] bf16, XOR-swizzled rows
  __shared__ __align__(16) u16 xc_t[2][1024];
  __shared__ __align__(4) u16 ptl[4][256];      // per-wave P^T (scaled, masked) [r][i]
  __shared__ float T1[16][9];
  __shared__ float T2[16][9];

  const int srow = tid >> 4;
  const int sbyte = (tid * 8) ^ ((srow & 7) << 4);

  uint2 sxb = *(const uint2*)(xbb + tid * 4);
  uint2 sxc = *(const uint2*)(xcb + tid * 4);

#pragma unroll 1
  for (int c = 0; c < 128; ++c) {
    const int cur = c & 1;
    *(uint2*)((char*)xb_t[cur] + sbyte) = sxb;
    *(uint2*)((char*)xc_t[cur] + sbyte) = sxc;
    __syncthreads();  // bar0: tiles staged
    if (c < 127) {
      sxb = *(const uint2*)(xbb + (c + 1) * 1024 + tid * 4);
      sxc = *(const uint2*)(xcb + (c + 1) * 1024 + tid * 4);
    }
    float co_own[4];
#pragma unroll
    for (int e = 0; e < 4; ++e) co_own[e] = cob[c * 16 + l4 * 4 + e];
    const float co15 = cob[c * 16 + 15];
    float xa_v[4];
#pragma unroll
    for (int e = 0; e < 4; ++e)
      xa_v[e] = bf2f(xab[(c * 16 + l4 * 4 + e) * 64 + col]);

    const u16* xbL = xb_t[cur];
    const u16* xcL = xc_t[cur];

    // W1 bf16 frags (rounded per chunk; master stays f32)
    bf16x8 w1f[2];
#pragma unroll
    for (int s = 0; s < 2; ++s)
#pragma unroll
      for (int e = 0; e < 8; ++e) w1f[s][e] = (short)f2bf(w1m[s][e]);
    // xb/xc row-l15 frags (A of Z1/xcW1, and B of Attn)
    bf16x8 xbr[2], xcr[2];
#pragma unroll
    for (int s = 0; s < 2; ++s) {
      const int byi = l15 * 128 + (((s * 64 + l4 * 16)) ^ ((l15 & 7) << 4));
      xbr[s] = *(const bf16x8*)((const char*)xbL + byi);
      xcr[s] = *(const bf16x8*)((const char*)xcL + byi);
    }

    // ---- Z1 = xb @ W1 + b1 (C layout: rows l4*4+e, col) ----
    f32x4 z = {b1c, b1c, b1c, b1c};
    z = mfma16(xbr[0], w1f[0], z);
    z = mfma16(xbr[1], w1f[1], z);

    // ---- LN stats round 1 (sum z, sum z^2 over cols) ----
    float sz[4], sz2[4];
#pragma unroll
    for (int e = 0; e < 4; ++e) { sz[e] = z[e]; sz2[e] = z[e] * z[e]; }
    bfly16(sz, sz2);
    if (l15 == 0) {
#pragma unroll
      for (int e = 0; e < 4; ++e) {
        T1[l4 * 4 + e][wq * 2] = sz[e];
        T1[l4 * 4 + e][wq * 2 + 1] = sz2[e];
      }
    }
    __syncthreads();  // bar1
    float mu[4], rstd[4], xhat[4], g[4];
#pragma unroll
    for (int e = 0; e < 4; ++e) {
      const int i = l4 * 4 + e;
      float a0 = 0.f, a1 = 0.f;
#pragma unroll
      for (int w2 = 0; w2 < 4; ++w2) { a0 += T1[i][w2 * 2]; a1 += T1[i][w2 * 2 + 1]; }
      mu[e] = a0 * 0.015625f;
      const float var = fmaxf(a1 * 0.015625f - mu[e] * mu[e], 0.f);
      rstd[e] = rsqrtf(var + 1e-6f);
      xhat[e] = (z[e] - mu[e]) * rstd[e];
      const float y = fmaf(lnw_c, xhat[e], lnb_c);
      const float tg = xa_v[e] - ld16s(xbL, i, col);
      g[e] = (y - tg) * lnw_c;
    }
    // ---- LN stats round 2 (sum g, sum g*xhat) ----
    float sg[4], sgx[4];
#pragma unroll
    for (int e = 0; e < 4; ++e) { sg[e] = g[e]; sgx[e] = g[e] * xhat[e]; }
    bfly16(sg, sgx);
    if (l15 == 0) {
#pragma unroll
      for (int e = 0; e < 4; ++e) {
        T2[l4 * 4 + e][wq * 2] = sg[e];
        T2[l4 * 4 + e][wq * 2 + 1] = sgx[e];
      }
    }
    __syncthreads();  // bar2
    float grad[4];
#pragma unroll
    for (int e = 0; e < 4; ++e) {
      const int i = l4 * 4 + e;
      float gs = 0.f, gx = 0.f;
#pragma unroll
      for (int w2 = 0; w2 < 4; ++w2) { gs += T2[i][w2 * 2]; gx += T2[i][w2 * 2 + 1]; }
      grad[e] = (64.f * g[e] - gs - xhat[e] * gx) * (rstd[e] * 0.015625f);
    }

    // ---- cross-lane grad: full column for this lane's col ----
    float g1[4], g2v[4], g3[4];
#pragma unroll
    for (int e = 0; e < 4; ++e) {
      g1[e] = __shfl_xor(grad[e], 16, 64);
      g2v[e] = __shfl_xor(grad[e], 32, 64);
      g3[e] = __shfl_xor(g1[e], 32, 64);
    }
    const float t_own = grad[0] + grad[1] + grad[2] + grad[3];
    const float t1 = g1[0] + g1[1] + g1[2] + g1[3];
    const float t2 = g2v[0] + g2v[1] + g2v[2] + g2v[3];
    const float t3 = g3[0] + g3[1] + g3[2] + g3[3];
    const float gtot = t_own + t1 + t2 + t3;
    float pfx[4];
    pfx[0] = grad[0];
    pfx[1] = pfx[0] + grad[1];
    pfx[2] = pfx[1] + grad[2];
    pfx[3] = pfx[2] + grad[3];
    const float off = ((l4 & 1) ? t1 : 0.f) + ((l4 & 2) ? (t2 + t3) : 0.f);
    float b1bar[4];
#pragma unroll
    for (int e = 0; e < 4; ++e) b1bar[e] = fmaf(-co_own[e], pfx[e] + off, b1c);

    // ---- grad as B-frag (rows l4*8+e of grad, this col) via bpermute ----
    const int aA = (((l4 << 1) * 16) + l15) << 2;
    const int aB = aA + 64;
    float pa[4], pb[4];
#pragma unroll
    for (int r = 0; r < 4; ++r) {
      pa[r] = __builtin_bit_cast(
          float, __builtin_amdgcn_ds_bpermute(aA, __builtin_bit_cast(int, grad[r])));
      pb[r] = __builtin_bit_cast(
          float, __builtin_amdgcn_ds_bpermute(aB, __builtin_bit_cast(int, grad[r])));
    }
    bf16x8 gfrag;
#pragma unroll
    for (int e = 0; e < 4; ++e) gfrag[e] = (short)f2bf(pa[e]);
#pragma unroll
    for (int e = 0; e < 4; ++e) gfrag[4 + e] = (short)f2bf(pb[e]);

    // ---- Attn = xc @ xb^T (each wave computes full 16x16) ----
    f32x4 p = {0.f, 0.f, 0.f, 0.f};
    p = mfma16(xcr[0], xbr[0], p);
    p = mfma16(xcr[1], xbr[1], p);
    // masked tril + scale by -co[row], write P^T to per-wave LDS
    u16* ptw = ptl[wq];
#pragma unroll
    for (int eh = 0; eh < 2; ++eh) {
      const int i0 = l4 * 4 + 2 * eh;
      const float v0 = (l15 <= i0) ? p[2 * eh] * (-co_own[2 * eh]) : 0.f;
      const float v1 = (l15 <= i0 + 1) ? p[2 * eh + 1] * (-co_own[2 * eh + 1]) : 0.f;
      const unsigned pk = (unsigned)f2bf(v0) | ((unsigned)f2bf(v1) << 16);
      *(unsigned*)&ptw[l15 * 16 + i0] = pk;
    }
    // A-frag of (-co*P): rows i=l15, k=r=l4*8+e (zero for k>=16)
    bf16x8 ptf;
#pragma unroll
    for (int e = 0; e < 8; ++e) {
      const int idx = (((l4 & 1) * 8 + e) * 16) + l15;  // in-bounds for all l4
      const u16 pv = (l4 < 2) ? ptw[idx] : (u16)0;
      ptf[e] = (short)pv;
    }

    // ---- Z1_bar = b1bar + xc@W1 + (-co*P)@grad (one acc chain) ----
    f32x4 o = {b1bar[0], b1bar[1], b1bar[2], b1bar[3]};
    o = mfma16(xcr[0], w1f[0], o);
    o = mfma16(xcr[1], w1f[1], o);
    o = mfma16(ptf, gfrag, o);

    // ---- LN stats round 3 on Z1_bar ----
#pragma unroll
    for (int e = 0; e < 4; ++e) { sz[e] = o[e]; sz2[e] = o[e] * o[e]; }
    bfly16(sz, sz2);
    if (l15 == 0) {
#pragma unroll
      for (int e = 0; e < 4; ++e) {
        T1[l4 * 4 + e][wq * 2] = sz[e];
        T1[l4 * 4 + e][wq * 2 + 1] = sz2[e];
      }
    }
    __syncthreads();  // bar3
#pragma unroll
    for (int e = 0; e < 4; ++e) {
      const int i = l4 * 4 + e;
      float a0 = 0.f, a1 = 0.f;
#pragma unroll
      for (int w2 = 0; w2 < 4; ++w2) { a0 += T1[i][w2 * 2]; a1 += T1[i][w2 * 2 + 1]; }
      const float mu2 = a0 * 0.015625f;
      const float var2 = fmaxf(a1 * 0.015625f - mu2 * mu2, 0.f);
      const float rstd2 = rsqrtf(var2 + 1e-6f);
      const float ov = ld16s(xcL, i, col) + fmaf(lnw_c, (o[e] - mu2) * rstd2, lnb_c);
      XCW[((size_t)(b * 2048 + c * 16 + i)) * 2048 + h * 64 + col] = f2bf(ov);
    }

    // ---- W1 / b1 update: w1m[s][e] -= co15 * sum_r xb[r][k] * grad[r][col] ----
    const float nc = -co15;
    float gg0[4], gg1[4], gg2[4], gg3[4];
#pragma unroll
    for (int e = 0; e < 4; ++e) {
      gg0[e] = grad[e] * nc; gg1[e] = g1[e] * nc; gg2[e] = g2v[e] * nc; gg3[e] = g3[e] * nc;
    }
#pragma unroll
    for (int gsel = 0; gsel < 4; ++gsel) {
#pragma unroll
      for (int e2 = 0; e2 < 4; ++e2) {
        const int r = ((l4 ^ gsel) << 2) + e2;
        const float gv = (gsel == 0) ? gg0[e2] : (gsel == 1) ? gg1[e2]
                         : (gsel == 2) ? gg2[e2] : gg3[e2];
#pragma unroll
        for (int s = 0; s < 2; ++s) {
          const int byi = r * 128 + (((s * 64 + l4 * 16)) ^ ((r & 7) << 4));
          const uint4 d = *(const uint4*)((const char*)xbL + byi);
          w1m[s][0] = fmaf(__builtin_bit_cast(float, d.x << 16), gv, w1m[s][0]);
          w1m[s][1] = fmaf(__builtin_bit_cast(float, d.x & 0xffff0000u), gv, w1m[s][1]);
          w1m[s][2] = fmaf(__builtin_bit_cast(float, d.y << 16), gv, w1m[s][2]);
          w1m[s][3] = fmaf(__builtin_bit_cast(float, d.y & 0xffff0000u), gv, w1m[s][3]);
          w1m[s][4] = fmaf(__builtin_bit_cast(float, d.z << 16), gv, w1m[s][4]);
          w1m[s][5] = fmaf(__builtin_bit_cast(float, d.z & 0xffff0000u), gv, w1m[s][5]);
          w1m[s][6] = fmaf(__builtin_bit_cast(float, d.w << 16), gv, w1m[s][6]);
          w1m[s][7] = fmaf(__builtin_bit_cast(float, d.w & 0xffff0000u), gv, w1m[s][7]);
        }
      }
    }
    b1c = fmaf(-co15, gtot, b1c);
  }
}

// ---------- launcher ----------
extern "C" void kernel_launch(void* const* d_in, const int* in_sizes, int n_in, void* d_out,
                              int out_size, void* d_ws, size_t ws_size, hipStream_t stream) {
  const float* hs = (const float*)d_in[0];
  const float* Wq = (const float*)d_in[1];
  const float* Wk = (const float*)d_in[2];
  const float* Wv = (const float*)d_in[3];
  const float* Wo = (const float*)d_in[4];
  const float* ilr_w = (const float*)d_in[5];
  const float* ilr_b = (const float*)d_in[6];
  const float* lnw = (const float*)d_in[7];
  const float* lnb = (const float*)d_in[8];
  const float* W1 = (const float*)d_in[9];
  const float* b1 = (const float*)d_in[10];
  float* out = (float*)d_out;

  if (ws_size < 93847552u) return;  // diagnosable clean-fail instead of device fault
  char* ws = (char*)d_ws;
  u16* hsb = (u16*)(ws + 0);                 // 33.5 MB; reused as XCW after gemm<0>
  u16* WcatT = (u16*)(ws + 33554432);        // 25.7 MB; reused as WoT after gemm<0>
  u16* XCbf = (u16*)(ws + 59244544);         // 33.5 MB
  float* coeffb = (float*)(ws + 92798976);   // 1 MB
  u16* XCW = hsb;
  u16* WoT = (u16*)(ws + 33554432);
  u16* XBbf = (u16*)d_out;                       // d_out as scratch (dead before gemm<1>)
  u16* XAbf = (u16*)((char*)d_out + 33554432);

  conv_bf16<<<8192, 256, 0, stream>>>(hs, hsb);
  wt_conv<<<dim3(32, 32), 256, 0, stream>>>(Wq, WcatT, 2048, 2048);
  wt_conv<<<dim3(32, 32), 256, 0, stream>>>(Wk, WcatT + (size_t)2048 * 2048, 2048, 2048);
  wt_conv<<<dim3(32, 32), 256, 0, stream>>>(Wv, WcatT + (size_t)4096 * 2048, 2048, 2048);
  ilr_strip<<<1024, 256, 0, stream>>>(ilr_w, WcatT);

  gemm_bt<0><<<dim3(49, 64), 256, 0, stream>>>(hsb, WcatT, 8192, 6272, 2048, XCbf, XBbf, XAbf,
                                               coeffb, ilr_b, nullptr);
  wt_conv<<<dim3(32, 32), 256, 0, stream>>>(Wo, WoT, 2048, 2048);
  ttt_scan<<<128, 256, 0, stream>>>(XCbf, XBbf, XAbf, coeffb, lnw, lnb, W1, b1, XCW);
  gemm_bt<1><<<dim3(16, 64), 256, 0, stream>>>(XCW, WoT, 8192, 2048, 2048, nullptr, nullptr,
                                               nullptr, nullptr, nullptr, out);

  (void)in_sizes; (void)n_in; (void)out_size;
}

// Round 6
// 880.017 us; speedup vs baseline: 1.7187x; 1.1080x over previous
//
#include <hip/hip_runtime.h>
#include <hip/hip_bf16.h>

// ---------- types ----------
typedef __attribute__((ext_vector_type(8))) short bf16x8;   // 8 bf16 in 4 VGPRs
typedef __attribute__((ext_vector_type(4))) float f32x4;
typedef __attribute__((ext_vector_type(8))) unsigned short u16x8;
typedef __attribute__((ext_vector_type(4))) unsigned short u16x4;
typedef unsigned short u16;

#define AS1(p) ((__attribute__((address_space(1))) void*)(p))
#define AS3(p) ((__attribute__((address_space(3))) void*)(p))
#define GLL16(g, l) __builtin_amdgcn_global_load_lds(AS1(g), AS3(l), 16, 0, 0)

__device__ __forceinline__ u16 f2bf(float x) {
  return __builtin_bit_cast(u16, __float2bfloat16(x));
}
__device__ __forceinline__ float bf2f(u16 u) {
  return __builtin_bit_cast(float, ((unsigned)u) << 16);
}
__device__ __forceinline__ unsigned pk2(float a, float b) {
  return (unsigned)f2bf(a) | ((unsigned)f2bf(b) << 16);
}
__device__ __forceinline__ f32x4 mfma16(bf16x8 a, bf16x8 b, f32x4 c) {
  return __builtin_amdgcn_mfma_f32_16x16x32_bf16(a, b, c, 0, 0, 0);
}
// sum over each 16-lane group (same l4) — R3-proven shfl_xor butterfly
__device__ __forceinline__ float rsum16(float x) {
  x += __shfl_xor(x, 1, 64);
  x += __shfl_xor(x, 2, 64);
  x += __shfl_xor(x, 4, 64);
  x += __shfl_xor(x, 8, 64);
  return x;
}
// compiler scheduling fence: nothing (incl. LDS ops) moves across
__device__ __forceinline__ void sfence() { __builtin_amdgcn_sched_barrier(0); }
// aliasing-legal LDS store/load (memcpy is char-based: ordering is mandatory)
template <typename T>
__device__ __forceinline__ void lds_st(u16* p, T v) {
  __builtin_memcpy((void*)p, &v, sizeof(T));
}
template <typename T>
__device__ __forceinline__ T lds_ld(const u16* p) {
  T v;
  __builtin_memcpy(&v, (const void*)p, sizeof(T));
  return v;
}

// ---------- convert hs f32 -> bf16 (8 elems/thread) ----------
__global__ __launch_bounds__(256) void conv_bf16(const float* __restrict__ in,
                                                 u16* __restrict__ out) {
  size_t g = (size_t)blockIdx.x * 256 + threadIdx.x;
  const float4* p = reinterpret_cast<const float4*>(in) + g * 2;
  float4 a = p[0], b = p[1];
  u16x8 r;
  r[0] = f2bf(a.x); r[1] = f2bf(a.y); r[2] = f2bf(a.z); r[3] = f2bf(a.w);
  r[4] = f2bf(b.x); r[5] = f2bf(b.y); r[6] = f2bf(b.z); r[7] = f2bf(b.w);
  *reinterpret_cast<u16x8*>(out + g * 8) = r;
}

// ---------- transpose + convert: W[K][N] f32 -> Wt[N][K] bf16 ----------
__global__ __launch_bounds__(256) void wt_conv(const float* __restrict__ W,
                                               u16* __restrict__ Wt, int Kd, int N) {
  __shared__ float t[64][65];
  const int n0 = blockIdx.x * 64, k0 = blockIdx.y * 64;
  const int tx = threadIdx.x & 63, ty = threadIdx.x >> 6;
#pragma unroll
  for (int rr = 0; rr < 16; ++rr) {
    int r = rr * 4 + ty;
    t[r][tx] = W[(size_t)(k0 + r) * N + n0 + tx];
  }
  __syncthreads();
#pragma unroll
  for (int rr = 0; rr < 16; ++rr) {
    int r = rr * 4 + ty;
    Wt[(size_t)(n0 + r) * Kd + k0 + tx] = f2bf(t[tx][r]);
  }
}

// ---------- ilr_w strip into WcatT rows [6144,6272) ----------
__global__ __launch_bounds__(256) void ilr_strip(const float* __restrict__ ilr_w,
                                                 u16* __restrict__ WcatT) {
  int g = blockIdx.x * 256 + threadIdx.x;  // 128*2048
  int p = g >> 11, k = g & 2047;
  float v = (p < 32) ? ilr_w[k * 32 + p] : 0.f;
  WcatT[(size_t)(6144 + p) * 2048 + k] = f2bf(v);
}

// ---------- staging: 128x32 bf16 tile per matrix ----------
__device__ __forceinline__ void stage_pair(const u16* __restrict__ A, const u16* __restrict__ Bt,
                                           u16* As, u16* Bs, int Kd, int mT, int nT, int kt,
                                           int tid) {
#pragma unroll
  for (int r = 0; r < 2; ++r) {
    int e = r * 2048 + tid * 8;
    int row = e >> 5, kk = e & 31;
    GLL16(A + (size_t)(mT + row) * Kd + kt + kk, As + e);
    GLL16(Bt + (size_t)(nT + row) * Kd + kt + kk, Bs + e);
  }
}

// ---------- MFMA GEMM  C[M][N] = A[M][Kd] * Bt[N][Kd]^T ----------
template <int MODE>
__global__ __launch_bounds__(256) void gemm_bt(const u16* __restrict__ A,
                                               const u16* __restrict__ Bt, int M, int N, int Kd,
                                               u16* __restrict__ O0, u16* __restrict__ O1,
                                               u16* __restrict__ O2,
                                               float* __restrict__ coeffOut,
                                               const float* __restrict__ ilrb,
                                               float* __restrict__ Cout) {
  __shared__ __align__(16) u16 As[2][4096];
  __shared__ __align__(16) u16 Bs[2][4096];
  const int tid = threadIdx.x;
  const int lane = tid & 63;
  const int wid = tid >> 6;
  const int wr = wid >> 1, wc = wid & 1;
  const int l15 = lane & 15, l4 = lane >> 4;
  const int mT = blockIdx.y << 7, nT = blockIdx.x << 7;

  f32x4 acc[4][4];
#pragma unroll
  for (int m = 0; m < 4; ++m)
#pragma unroll
    for (int n = 0; n < 4; ++n) acc[m][n] = (f32x4){0.f, 0.f, 0.f, 0.f};

  stage_pair(A, Bt, &As[0][0], &Bs[0][0], Kd, mT, nT, 0, tid);
  const int nIter = Kd >> 5;
  const int aoff = (wr * 64 + l15) * 32 + l4 * 8;
  const int boff = (wc * 64 + l15) * 32 + l4 * 8;
#pragma unroll 1
  for (int it = 0; it < nIter; ++it) {
    const int cur = it & 1;
    __syncthreads();
    if (it + 1 < nIter)
      stage_pair(A, Bt, &As[cur ^ 1][0], &Bs[cur ^ 1][0], Kd, mT, nT, (it + 1) << 5, tid);
    bf16x8 av[4], bv[4];
#pragma unroll
    for (int x = 0; x < 4; ++x) {
      av[x] = *reinterpret_cast<const bf16x8*>(&As[cur][aoff + x * 512]);
      bv[x] = *reinterpret_cast<const bf16x8*>(&Bs[cur][boff + x * 512]);
    }
#pragma unroll
    for (int m = 0; m < 4; ++m)
#pragma unroll
      for (int n = 0; n < 4; ++n) acc[m][n] = mfma16(av[m], bv[n], acc[m][n]);
  }
#pragma unroll
  for (int m = 0; m < 4; ++m) {
#pragma unroll
    for (int n = 0; n < 4; ++n) {
      const int col = nT + wc * 64 + n * 16 + l15;
#pragma unroll
      for (int e = 0; e < 4; ++e) {
        const int row = mT + wr * 64 + m * 16 + l4 * 4 + e;
        float v = acc[m][n][e];
        if constexpr (MODE == 1) {
          Cout[(size_t)row * N + col] = v;
        } else {
          const int bb = row >> 11, lt = row & 2047;
          if (col < 6144) {
            const int mat = col >> 11;
            u16* base = (mat == 0) ? O0 : ((mat == 1) ? O1 : O2);
            const int hh = (col >> 6) & 31, dd = col & 63;
            base[(((size_t)(bb * 32 + hh)) * 2048 + lt) * 64 + dd] = f2bf(v);
          } else {
            const int h3 = col - 6144;
            if (h3 < 32) {
              const float x = v + ilrb[h3];
              const float sig = 1.f / (1.f + expf(-x));
              const int tok = lt & 15;
              coeffOut[((size_t)(bb * 32 + h3)) * 2048 + lt] =
                  sig * (1.f / (64.f * (float)(tok + 1)));
            }
          }
        }
      }
    }
  }
  (void)M;
}

// ---------- 1-wave-per-(b,h) TTT scan: no barriers, W1 in MFMA C-layout regs ----------
// lane: l15 = lane&15, l4 = lane>>4. C-layout: row = l4*4+e, col(tile cb) = cb*16+l15.
// A/B-frag: row/col = l15, k = l4*8+e (+32s). mW[kb][cb][e] = W1[kb*16+l4*4+e][cb*16+l15].
// All LDS round-trips via memcpy (aliasing-legal) + sched_barrier fences (R4/R5 NaN
// root-cause theory: TBAA let the scheduler lift ds_read above the ds_write).
__global__ __launch_bounds__(64) void ttt_scan(
    const u16* __restrict__ XC, const u16* __restrict__ XB, const u16* __restrict__ XA,
    const float* __restrict__ coeff, const float* __restrict__ lnw_g,
    const float* __restrict__ lnb_g, const float* __restrict__ W1g,
    const float* __restrict__ b1g, u16* __restrict__ XCW) {
  const int bh = blockIdx.x;
  const int b = bh >> 5, h = bh & 31;
  const int lane = threadIdx.x & 63;
  const int l15 = lane & 15, l4 = lane >> 4;
  const bool klo = (l4 < 2);  // lanes whose frag k-slots (l4*8+e) are < 16

  const u16* xbb = XB + (size_t)bh * 131072;
  const u16* xcb = XC + (size_t)bh * 131072;
  const u16* xab = XA + (size_t)bh * 131072;
  const float* cob = coeff + (size_t)bh * 2048;

  float lnw4[4], lnb4[4], b1m[4];
#pragma unroll
  for (int cb = 0; cb < 4; ++cb) {
    lnw4[cb] = lnw_g[h * 64 + cb * 16 + l15];
    lnb4[cb] = lnb_g[h * 64 + cb * 16 + l15];
    b1m[cb] = b1g[h * 64 + cb * 16 + l15];
  }
  f32x4 mW[4][4];
#pragma unroll
  for (int kb = 0; kb < 4; ++kb)
#pragma unroll
    for (int cb = 0; cb < 4; ++cb)
#pragma unroll
      for (int e = 0; e < 4; ++e)
        mW[kb][cb][e] = W1g[(size_t)h * 4096 + (kb * 16 + l4 * 4 + e) * 64 + cb * 16 + l15];

  __shared__ __align__(16) u16 w1L[64 * 72];   // [col][k] W1^T bf16, stride 72
  __shared__ __align__(16) u16 xbTs[64 * 24];  // [col][r] (-co15*xb)^T bf16, stride 24
  __shared__ __align__(16) u16 gTs[64 * 24];   // [col][r] grad^T bf16, stride 24
  __shared__ __align__(4) u16 ptw[256];        // P^T [col][row] (masked, -co-scaled)

  // prefetch chunk 0
  uint4 nfb0, nfb1, nfc0, nfc1;
  float nco[4], nco15;
  {
    const char* pb = (const char*)xbb;
    const char* pc = (const char*)xcb;
    const int fo = l15 * 128 + l4 * 16;
    nfb0 = *(const uint4*)(pb + fo); nfb1 = *(const uint4*)(pb + fo + 64);
    nfc0 = *(const uint4*)(pc + fo); nfc1 = *(const uint4*)(pc + fo + 64);
#pragma unroll
    for (int e = 0; e < 4; ++e) nco[e] = cob[l4 * 4 + e];
    nco15 = cob[15];
  }

#pragma unroll 1
  for (int c = 0; c < 128; ++c) {
    const bf16x8 xbr0 = __builtin_bit_cast(bf16x8, nfb0);
    const bf16x8 xbr1 = __builtin_bit_cast(bf16x8, nfb1);
    const bf16x8 xcr0 = __builtin_bit_cast(bf16x8, nfc0);
    const bf16x8 xcr1 = __builtin_bit_cast(bf16x8, nfc1);
    float co_own[4];
#pragma unroll
    for (int e = 0; e < 4; ++e) co_own[e] = nco[e];
    const float co15 = nco15;

    // prefetch chunk c+1 (T14: hidden under this chunk's compute)
    {
      const int cc = (c < 127) ? (c + 1) : 127;
      const char* pb = (const char*)(xbb + cc * 1024);
      const char* pc = (const char*)(xcb + cc * 1024);
      const int fo = l15 * 128 + l4 * 16;
      nfb0 = *(const uint4*)(pb + fo); nfb1 = *(const uint4*)(pb + fo + 64);
      nfc0 = *(const uint4*)(pc + fo); nfc1 = *(const uint4*)(pc + fo + 64);
#pragma unroll
      for (int e = 0; e < 4; ++e) nco[e] = cob[cc * 16 + l4 * 4 + e];
      nco15 = cob[cc * 16 + 15];
    }

    // ---- Attn = xc @ xb^T (frags double as A and B operands) ----
    f32x4 p = {0.f, 0.f, 0.f, 0.f};
    p = mfma16(xcr0, xbr0, p);
    p = mfma16(xcr1, xbr1, p);
    // mask tril, scale rows by -co[row], store P^T to LDS
#pragma unroll
    for (int eh = 0; eh < 2; ++eh) {
      const int i0 = l4 * 4 + 2 * eh;
      const float v0 = (l15 <= i0) ? p[2 * eh] * (-co_own[2 * eh]) : 0.f;
      const float v1 = (l15 <= i0 + 1) ? p[2 * eh + 1] * (-co_own[2 * eh + 1]) : 0.f;
      lds_st<unsigned>(&ptw[l15 * 16 + i0], pk2(v0, v1));
    }

    // ---- stage (-co15 * xb)^T for the W1-update A-operand ----
    {
      const u16* xbrow = xbb + c * 1024;
      u16 xv[16];
#pragma unroll
      for (int r = 0; r < 16; ++r) xv[r] = xbrow[r * 64 + lane];  // coalesced 128B rows
      const float s = -co15;
#pragma unroll
      for (int r2 = 0; r2 < 4; ++r2) {
        u16x4 w;
#pragma unroll
        for (int i = 0; i < 4; ++i) w[i] = f2bf(bf2f(xv[r2 * 4 + i]) * s);
        lds_st<u16x4>(&xbTs[lane * 24 + r2 * 4], w);
      }
    }

    // ---- W1 master (C-layout f32) -> bf16 B-frags via LDS round trip ----
#pragma unroll
    for (int kb = 0; kb < 4; ++kb)
#pragma unroll
      for (int cb = 0; cb < 4; ++cb) {
        u16x4 w;
#pragma unroll
        for (int e = 0; e < 4; ++e) w[e] = f2bf(mW[kb][cb][e]);
        lds_st<u16x4>(&w1L[(cb * 16 + l15) * 72 + kb * 16 + l4 * 4], w);
      }
    sfence();  // all w1L writes complete before w1f reads
    bf16x8 w1f[4][2];
#pragma unroll
    for (int cb = 0; cb < 4; ++cb)
#pragma unroll
      for (int s = 0; s < 2; ++s)
        w1f[cb][s] = lds_ld<bf16x8>(&w1L[(cb * 16 + l15) * 72 + s * 32 + l4 * 8]);
    sfence();

    // ---- Z1 = xb @ W1 + b1 ----
    f32x4 z[4];
#pragma unroll
    for (int cb = 0; cb < 4; ++cb) {
      f32x4 acc = {b1m[cb], b1m[cb], b1m[cb], b1m[cb]};
      acc = mfma16(xbr0, w1f[cb][0], acc);
      z[cb] = mfma16(xbr1, w1f[cb][1], acc);
    }
    // ---- xc @ W1 (independent of LN chain; overlaps it) ----
    f32x4 o2[4];
#pragma unroll
    for (int cb = 0; cb < 4; ++cb) {
      f32x4 acc = {0.f, 0.f, 0.f, 0.f};
      acc = mfma16(xcr0, w1f[cb][0], acc);
      o2[cb] = mfma16(xcr1, w1f[cb][1], acc);
    }

    // ---- C-layout loads: target (xa-xb) and xc residual ----
    const u16* xap = xab + c * 1024;
    const u16* xbp = xbb + c * 1024;
    const u16* xcp = xcb + c * 1024;
    float tgt[4][4], xcC[4][4];
#pragma unroll
    for (int cb = 0; cb < 4; ++cb)
#pragma unroll
      for (int e = 0; e < 4; ++e) {
        const int idx = (l4 * 4 + e) * 64 + cb * 16 + l15;
        tgt[cb][e] = bf2f(xap[idx]) - bf2f(xbp[idx]);
        xcC[cb][e] = bf2f(xcp[idx]);
      }

    // ---- LN backward: stats via shfl_xor 16-group reductions ----
    float xhat[4][4], gr[4][4];
#pragma unroll
    for (int e = 0; e < 4; ++e) {
      float s1 = z[0][e] + z[1][e] + z[2][e] + z[3][e];
      float s2 = z[0][e] * z[0][e] + z[1][e] * z[1][e] + z[2][e] * z[2][e] + z[3][e] * z[3][e];
      s1 = rsum16(s1);
      s2 = rsum16(s2);
      const float mu = s1 * 0.015625f;
      const float var = fmaxf(s2 * 0.015625f - mu * mu, 0.f);
      const float rstd = rsqrtf(var + 1e-6f);
      float gloc[4];
#pragma unroll
      for (int cb = 0; cb < 4; ++cb) {
        xhat[cb][e] = (z[cb][e] - mu) * rstd;
        gloc[cb] = (fmaf(lnw4[cb], xhat[cb][e], lnb4[cb]) - tgt[cb][e]) * lnw4[cb];
      }
      float gs = gloc[0] + gloc[1] + gloc[2] + gloc[3];
      float gx = gloc[0] * xhat[0][e] + gloc[1] * xhat[1][e] + gloc[2] * xhat[2][e] +
                 gloc[3] * xhat[3][e];
      gs = rsum16(gs);
      gx = rsum16(gx);
#pragma unroll
      for (int cb = 0; cb < 4; ++cb)
        gr[cb][e] = (64.f * gloc[cb] - gs - xhat[cb][e] * gx) * (rstd * 0.015625f);
    }

    // ---- column totals / prefix (for b1_bar, b1 update) ----
    float gtot[4], lower[4];
#pragma unroll
    for (int cb = 0; cb < 4; ++cb) {
      const float T = gr[cb][0] + gr[cb][1] + gr[cb][2] + gr[cb][3];
      const float t1 = __shfl_xor(T, 16, 64);
      const float t2 = __shfl_xor(T, 32, 64);
      const float t3 = __shfl_xor(t1, 32, 64);
      gtot[cb] = T + t1 + t2 + t3;
      lower[cb] = ((l4 & 1) ? t1 : 0.f) + ((l4 & 2) ? (t2 + t3) : 0.f);
    }

    // ---- grad^T to LDS -> B-frags (for P@grad and W1 update) ----
#pragma unroll
    for (int cb = 0; cb < 4; ++cb) {
      uint2 w = {pk2(gr[cb][0], gr[cb][1]), pk2(gr[cb][2], gr[cb][3])};
      lds_st<uint2>(&gTs[(cb * 16 + l15) * 24 + l4 * 4], w);
    }
    sfence();  // gTs/xbTs/ptw writes complete before frag reads
    bf16x8 gf[4];
    const bf16x8 zero8 = {};
#pragma unroll
    for (int cb = 0; cb < 4; ++cb) {
      bf16x8 v = lds_ld<bf16x8>(&gTs[(cb * 16 + l15) * 24 + (l4 & 1) * 8]);
      gf[cb] = klo ? v : zero8;
    }
    // P^T A-frag (K=32, upper 16 zero)
    bf16x8 ptf;
#pragma unroll
    for (int e = 0; e < 8; ++e) {
      const u16 pv = klo ? ptw[(((l4 & 1) * 8 + e) * 16) + l15] : (u16)0;
      ptf[e] = (short)pv;
    }
    sfence();

    // ---- Z1_bar = xc@W1 + (-co*P)@grad + b1_bar; LN fwd; output ----
#pragma unroll
    for (int cb = 0; cb < 4; ++cb) o2[cb] = mfma16(ptf, gf[cb], o2[cb]);
    float ov[4][4];
#pragma unroll
    for (int cb = 0; cb < 4; ++cb) {
      float pfx = lower[cb];
#pragma unroll
      for (int e = 0; e < 4; ++e) {
        pfx += gr[cb][e];
        ov[cb][e] = o2[cb][e] + fmaf(-co_own[e], pfx, b1m[cb]);
      }
    }
#pragma unroll
    for (int e = 0; e < 4; ++e) {
      float s1 = ov[0][e] + ov[1][e] + ov[2][e] + ov[3][e];
      float s2 = ov[0][e] * ov[0][e] + ov[1][e] * ov[1][e] + ov[2][e] * ov[2][e] +
                 ov[3][e] * ov[3][e];
      s1 = rsum16(s1);
      s2 = rsum16(s2);
      const float mu = s1 * 0.015625f;
      const float var = fmaxf(s2 * 0.015625f - mu * mu, 0.f);
      const float rstd = rsqrtf(var + 1e-6f);
      const size_t rowg = (size_t)(b * 2048 + c * 16 + l4 * 4 + e) * 2048 + h * 64;
#pragma unroll
      for (int cb = 0; cb < 4; ++cb) {
        const float y = xcC[cb][e] + fmaf(lnw4[cb], (ov[cb][e] - mu) * rstd, lnb4[cb]);
        XCW[rowg + cb * 16 + l15] = f2bf(y);
      }
    }

    // ---- W1 update: mW += (-co15*xb)^T @ grad  (16 MFMAs into the master) ----
    bf16x8 xbtf[4];
#pragma unroll
    for (int kb = 0; kb < 4; ++kb) {
      bf16x8 v = lds_ld<bf16x8>(&xbTs[(kb * 16 + l15) * 24 + (l4 & 1) * 8]);
      xbtf[kb] = klo ? v : zero8;
    }
    sfence();
#pragma unroll
    for (int kb = 0; kb < 4; ++kb)
#pragma unroll
      for (int cb = 0; cb < 4; ++cb) mW[kb][cb] = mfma16(xbtf[kb], gf[cb], mW[kb][cb]);
    // b1 update
#pragma unroll
    for (int cb = 0; cb < 4; ++cb) b1m[cb] = fmaf(-co15, gtot[cb], b1m[cb]);
    sfence();  // keep next iteration's LDS writes behind this iteration's reads
  }
}

// ---------- launcher ----------
extern "C" void kernel_launch(void* const* d_in, const int* in_sizes, int n_in, void* d_out,
                              int out_size, void* d_ws, size_t ws_size, hipStream_t stream) {
  const float* hs = (const float*)d_in[0];
  const float* Wq = (const float*)d_in[1];
  const float* Wk = (const float*)d_in[2];
  const float* Wv = (const float*)d_in[3];
  const float* Wo = (const float*)d_in[4];
  const float* ilr_w = (const float*)d_in[5];
  const float* ilr_b = (const float*)d_in[6];
  const float* lnw = (const float*)d_in[7];
  const float* lnb = (const float*)d_in[8];
  const float* W1 = (const float*)d_in[9];
  const float* b1 = (const float*)d_in[10];
  float* out = (float*)d_out;

  if (ws_size < 93847552u) return;  // diagnosable clean-fail instead of device fault
  char* ws = (char*)d_ws;
  u16* hsb = (u16*)(ws + 0);                 // 33.5 MB; reused as XCW after gemm<0>
  u16* WcatT = (u16*)(ws + 33554432);        // 25.7 MB; reused as WoT after gemm<0>
  u16* XCbf = (u16*)(ws + 59244544);         // 33.5 MB
  float* coeffb = (float*)(ws + 92798976);   // 1 MB
  u16* XCW = hsb;
  u16* WoT = (u16*)(ws + 33554432);
  u16* XBbf = (u16*)d_out;                       // d_out as scratch (dead before gemm<1>)
  u16* XAbf = (u16*)((char*)d_out + 33554432);

  conv_bf16<<<8192, 256, 0, stream>>>(hs, hsb);
  wt_conv<<<dim3(32, 32), 256, 0, stream>>>(Wq, WcatT, 2048, 2048);
  wt_conv<<<dim3(32, 32), 256, 0, stream>>>(Wk, WcatT + (size_t)2048 * 2048, 2048, 2048);
  wt_conv<<<dim3(32, 32), 256, 0, stream>>>(Wv, WcatT + (size_t)4096 * 2048, 2048, 2048);
  ilr_strip<<<1024, 256, 0, stream>>>(ilr_w, WcatT);

  gemm_bt<0><<<dim3(49, 64), 256, 0, stream>>>(hsb, WcatT, 8192, 6272, 2048, XCbf, XBbf, XAbf,
                                               coeffb, ilr_b, nullptr);
  wt_conv<<<dim3(32, 32), 256, 0, stream>>>(Wo, WoT, 2048, 2048);
  ttt_scan<<<128, 64, 0, stream>>>(XCbf, XBbf, XAbf, coeffb, lnw, lnb, W1, b1, XCW);
  gemm_bt<1><<<dim3(16, 64), 256, 0, stream>>>(XCW, WoT, 8192, 2048, 2048, nullptr, nullptr,
                                               nullptr, nullptr, nullptr, out);

  (void)in_sizes; (void)n_in; (void)out_size;
}

// Round 7
// 800.137 us; speedup vs baseline: 1.8902x; 1.0998x over previous
//
#include <hip/hip_runtime.h>
#include <hip/hip_bf16.h>

// ---------- types ----------
typedef __attribute__((ext_vector_type(8))) short bf16x8;   // 8 bf16 in 4 VGPRs
typedef __attribute__((ext_vector_type(4))) float f32x4;
typedef __attribute__((ext_vector_type(8))) unsigned short u16x8;
typedef __attribute__((ext_vector_type(4))) unsigned short u16x4;
typedef unsigned short u16;

#define AS1(p) ((__attribute__((address_space(1))) void*)(p))
#define AS3(p) ((__attribute__((address_space(3))) void*)(p))
#define GLL16(g, l) __builtin_amdgcn_global_load_lds(AS1(g), AS3(l), 16, 0, 0)

__device__ __forceinline__ u16 f2bf(float x) {
  return __builtin_bit_cast(u16, __float2bfloat16(x));
}
__device__ __forceinline__ float bf2f(u16 u) {
  return __builtin_bit_cast(float, ((unsigned)u) << 16);
}
__device__ __forceinline__ unsigned pk2(float a, float b) {
  return (unsigned)f2bf(a) | ((unsigned)f2bf(b) << 16);
}
__device__ __forceinline__ f32x4 mfma16(bf16x8 a, bf16x8 b, f32x4 c) {
  return __builtin_amdgcn_mfma_f32_16x16x32_bf16(a, b, c, 0, 0, 0);
}
// sum over each 16-lane group (same l4) — shfl_xor butterfly
__device__ __forceinline__ float rsum16(float x) {
  x += __shfl_xor(x, 1, 64);
  x += __shfl_xor(x, 2, 64);
  x += __shfl_xor(x, 4, 64);
  x += __shfl_xor(x, 8, 64);
  return x;
}
// DS-only scheduling fence: VALU/SALU/MFMA/VMEM may cross, DS ops may not.
// (masks per T19: ALU 1|VALU 2|SALU 4|MFMA 8|VMEM 10|VMEM_RD 20|VMEM_WR 40)
__device__ __forceinline__ void dsfence() { __builtin_amdgcn_sched_barrier(0x7F); }
// aliasing-legal LDS store/load (memcpy is char-based: ordering is mandatory)
template <typename T>
__device__ __forceinline__ void lds_st(u16* p, T v) {
  __builtin_memcpy((void*)p, &v, sizeof(T));
}
template <typename T>
__device__ __forceinline__ T lds_ld(const u16* p) {
  T v;
  __builtin_memcpy(&v, (const void*)p, sizeof(T));
  return v;
}

// ---------- convert hs f32 -> bf16 (8 elems/thread) ----------
__global__ __launch_bounds__(256) void conv_bf16(const float* __restrict__ in,
                                                 u16* __restrict__ out) {
  size_t g = (size_t)blockIdx.x * 256 + threadIdx.x;
  const float4* p = reinterpret_cast<const float4*>(in) + g * 2;
  float4 a = p[0], b = p[1];
  u16x8 r;
  r[0] = f2bf(a.x); r[1] = f2bf(a.y); r[2] = f2bf(a.z); r[3] = f2bf(a.w);
  r[4] = f2bf(b.x); r[5] = f2bf(b.y); r[6] = f2bf(b.z); r[7] = f2bf(b.w);
  *reinterpret_cast<u16x8*>(out + g * 8) = r;
}

// ---------- transpose + convert: W[K][N] f32 -> Wt[N][K] bf16 ----------
__global__ __launch_bounds__(256) void wt_conv(const float* __restrict__ W,
                                               u16* __restrict__ Wt, int Kd, int N) {
  __shared__ float t[64][65];
  const int n0 = blockIdx.x * 64, k0 = blockIdx.y * 64;
  const int tx = threadIdx.x & 63, ty = threadIdx.x >> 6;
#pragma unroll
  for (int rr = 0; rr < 16; ++rr) {
    int r = rr * 4 + ty;
    t[r][tx] = W[(size_t)(k0 + r) * N + n0 + tx];
  }
  __syncthreads();
#pragma unroll
  for (int rr = 0; rr < 16; ++rr) {
    int r = rr * 4 + ty;
    Wt[(size_t)(n0 + r) * Kd + k0 + tx] = f2bf(t[tx][r]);
  }
}

// ---------- ilr_w strip into WcatT rows [6144,6272) ----------
__global__ __launch_bounds__(256) void ilr_strip(const float* __restrict__ ilr_w,
                                                 u16* __restrict__ WcatT) {
  int g = blockIdx.x * 256 + threadIdx.x;  // 128*2048
  int p = g >> 11, k = g & 2047;
  float v = (p < 32) ? ilr_w[k * 32 + p] : 0.f;
  WcatT[(size_t)(6144 + p) * 2048 + k] = f2bf(v);
}

// ---------- staging: 128x32 bf16 tile per matrix ----------
__device__ __forceinline__ void stage_pair(const u16* __restrict__ A, const u16* __restrict__ Bt,
                                           u16* As, u16* Bs, int Kd, int mT, int nT, int kt,
                                           int tid) {
#pragma unroll
  for (int r = 0; r < 2; ++r) {
    int e = r * 2048 + tid * 8;
    int row = e >> 5, kk = e & 31;
    GLL16(A + (size_t)(mT + row) * Kd + kt + kk, As + e);
    GLL16(Bt + (size_t)(nT + row) * Kd + kt + kk, Bs + e);
  }
}

// ---------- MFMA GEMM  C[M][N] = A[M][Kd] * Bt[N][Kd]^T ----------
template <int MODE>
__global__ __launch_bounds__(256) void gemm_bt(const u16* __restrict__ A,
                                               const u16* __restrict__ Bt, int M, int N, int Kd,
                                               u16* __restrict__ O0, u16* __restrict__ O1,
                                               u16* __restrict__ O2,
                                               float* __restrict__ coeffOut,
                                               const float* __restrict__ ilrb,
                                               float* __restrict__ Cout) {
  __shared__ __align__(16) u16 As[2][4096];
  __shared__ __align__(16) u16 Bs[2][4096];
  const int tid = threadIdx.x;
  const int lane = tid & 63;
  const int wid = tid >> 6;
  const int wr = wid >> 1, wc = wid & 1;
  const int l15 = lane & 15, l4 = lane >> 4;
  const int mT = blockIdx.y << 7, nT = blockIdx.x << 7;

  f32x4 acc[4][4];
#pragma unroll
  for (int m = 0; m < 4; ++m)
#pragma unroll
    for (int n = 0; n < 4; ++n) acc[m][n] = (f32x4){0.f, 0.f, 0.f, 0.f};

  stage_pair(A, Bt, &As[0][0], &Bs[0][0], Kd, mT, nT, 0, tid);
  const int nIter = Kd >> 5;
  const int aoff = (wr * 64 + l15) * 32 + l4 * 8;
  const int boff = (wc * 64 + l15) * 32 + l4 * 8;
#pragma unroll 1
  for (int it = 0; it < nIter; ++it) {
    const int cur = it & 1;
    __syncthreads();
    if (it + 1 < nIter)
      stage_pair(A, Bt, &As[cur ^ 1][0], &Bs[cur ^ 1][0], Kd, mT, nT, (it + 1) << 5, tid);
    bf16x8 av[4], bv[4];
#pragma unroll
    for (int x = 0; x < 4; ++x) {
      av[x] = *reinterpret_cast<const bf16x8*>(&As[cur][aoff + x * 512]);
      bv[x] = *reinterpret_cast<const bf16x8*>(&Bs[cur][boff + x * 512]);
    }
#pragma unroll
    for (int m = 0; m < 4; ++m)
#pragma unroll
      for (int n = 0; n < 4; ++n) acc[m][n] = mfma16(av[m], bv[n], acc[m][n]);
  }
#pragma unroll
  for (int m = 0; m < 4; ++m) {
#pragma unroll
    for (int n = 0; n < 4; ++n) {
      const int col = nT + wc * 64 + n * 16 + l15;
#pragma unroll
      for (int e = 0; e < 4; ++e) {
        const int row = mT + wr * 64 + m * 16 + l4 * 4 + e;
        float v = acc[m][n][e];
        if constexpr (MODE == 1) {
          Cout[(size_t)row * N + col] = v;
        } else {
          const int bb = row >> 11, lt = row & 2047;
          if (col < 6144) {
            const int mat = col >> 11;
            u16* base = (mat == 0) ? O0 : ((mat == 1) ? O1 : O2);
            const int hh = (col >> 6) & 31, dd = col & 63;
            base[(((size_t)(bb * 32 + hh)) * 2048 + lt) * 64 + dd] = f2bf(v);
          } else {
            const int h3 = col - 6144;
            if (h3 < 32) {
              const float x = v + ilrb[h3];
              const float sig = 1.f / (1.f + expf(-x));
              const int tok = lt & 15;
              coeffOut[((size_t)(bb * 32 + h3)) * 2048 + lt] =
                  sig * (1.f / (64.f * (float)(tok + 1)));
            }
          }
        }
      }
    }
  }
  (void)M;
}

// ---------- 1-wave-per-(b,h) TTT scan: no barriers, W1 in MFMA C-layout regs ----------
// lane: l15 = lane&15, l4 = lane>>4. C-layout: row = l4*4+e, col(tile cb) = cb*16+l15.
// A/B-frag: row/col = l15, k = l4*8+e (+32s). mW[kb][cb][e] = W1[kb*16+l4*4+e][cb*16+l15].
// LDS round-trips via memcpy (aliasing-legal). dsfence (DS-only sched barrier) keeps
// write->read DS order while letting VALU/MFMA/VMEM overlap the waits (R6: sched_barrier(0)
// serialized everything -> 94% idle). All per-chunk globals prefetched one chunk ahead.
__global__ __launch_bounds__(64) void ttt_scan(
    const u16* __restrict__ XC, const u16* __restrict__ XB, const u16* __restrict__ XA,
    const float* __restrict__ coeff, const float* __restrict__ lnw_g,
    const float* __restrict__ lnb_g, const float* __restrict__ W1g,
    const float* __restrict__ b1g, u16* __restrict__ XCW) {
  const int bh = blockIdx.x;
  const int b = bh >> 5, h = bh & 31;
  const int lane = threadIdx.x & 63;
  const int l15 = lane & 15, l4 = lane >> 4;
  const bool klo = (l4 < 2);  // lanes whose frag k-slots (l4*8+e) are < 16

  const u16* xbb = XB + (size_t)bh * 131072;
  const u16* xcb = XC + (size_t)bh * 131072;
  const u16* xab = XA + (size_t)bh * 131072;
  const float* cob = coeff + (size_t)bh * 2048;

  float lnw4[4], lnb4[4], b1m[4];
#pragma unroll
  for (int cb = 0; cb < 4; ++cb) {
    lnw4[cb] = lnw_g[h * 64 + cb * 16 + l15];
    lnb4[cb] = lnb_g[h * 64 + cb * 16 + l15];
    b1m[cb] = b1g[h * 64 + cb * 16 + l15];
  }
  f32x4 mW[4][4];
#pragma unroll
  for (int kb = 0; kb < 4; ++kb)
#pragma unroll
    for (int cb = 0; cb < 4; ++cb)
#pragma unroll
      for (int e = 0; e < 4; ++e)
        mW[kb][cb][e] = W1g[(size_t)h * 4096 + (kb * 16 + l4 * 4 + e) * 64 + cb * 16 + l15];

  __shared__ __align__(16) u16 w1L[64 * 72];   // [col][k] W1^T bf16, stride 72
  __shared__ __align__(16) u16 xbTs[64 * 24];  // [col][r] (-co15*xb)^T bf16, stride 24
  __shared__ __align__(16) u16 gTs[64 * 24];   // [col][r] grad^T bf16, stride 24
  __shared__ __align__(16) u16 ptw[256];       // P [i][j] (masked, -co[i]-scaled)

  // ---- chunk-ahead prefetch state (frags + C-layout scalars + xv rows + coeff) ----
  uint4 nfb0, nfb1, nfc0, nfc1;
  float nco[4], nco15;
  u16 nxa[4][4], nxbC[4][4], nxcC[4][4], nxv[16];
  const int fo = l15 * 128 + l4 * 16;
#define PREFETCH(cc)                                                                 \
  do {                                                                               \
    const char* pb = (const char*)(xbb + (cc) * 1024);                               \
    const char* pc = (const char*)(xcb + (cc) * 1024);                               \
    nfb0 = *(const uint4*)(pb + fo); nfb1 = *(const uint4*)(pb + fo + 64);           \
    nfc0 = *(const uint4*)(pc + fo); nfc1 = *(const uint4*)(pc + fo + 64);           \
    const u16* xap_ = xab + (cc) * 1024;                                             \
    const u16* xbp_ = xbb + (cc) * 1024;                                             \
    const u16* xcp_ = xcb + (cc) * 1024;                                             \
    _Pragma("unroll") for (int cb = 0; cb < 4; ++cb)                                 \
        _Pragma("unroll") for (int e = 0; e < 4; ++e) {                              \
      const int idx = (l4 * 4 + e) * 64 + cb * 16 + l15;                             \
      nxa[cb][e] = xap_[idx];                                                        \
      nxbC[cb][e] = xbp_[idx];                                                       \
      nxcC[cb][e] = xcp_[idx];                                                       \
    }                                                                                \
    _Pragma("unroll") for (int r = 0; r < 16; ++r) nxv[r] = xbp_[r * 64 + lane];     \
    _Pragma("unroll") for (int e = 0; e < 4; ++e) nco[e] = cob[(cc) * 16 + l4 * 4 + e]; \
    nco15 = cob[(cc) * 16 + 15];                                                     \
  } while (0)

  PREFETCH(0);

#pragma unroll 1
  for (int c = 0; c < 128; ++c) {
    const bf16x8 xbr0 = __builtin_bit_cast(bf16x8, nfb0);
    const bf16x8 xbr1 = __builtin_bit_cast(bf16x8, nfb1);
    const bf16x8 xcr0 = __builtin_bit_cast(bf16x8, nfc0);
    const bf16x8 xcr1 = __builtin_bit_cast(bf16x8, nfc1);
    float co_own[4];
#pragma unroll
    for (int e = 0; e < 4; ++e) co_own[e] = nco[e];
    const float co15 = nco15;
    float tgt[4][4], xcC[4][4];
#pragma unroll
    for (int cb = 0; cb < 4; ++cb)
#pragma unroll
      for (int e = 0; e < 4; ++e) {
        tgt[cb][e] = bf2f(nxa[cb][e]) - bf2f(nxbC[cb][e]);
        xcC[cb][e] = bf2f(nxcC[cb][e]);
      }
    u16 xv[16];
#pragma unroll
    for (int r = 0; r < 16; ++r) xv[r] = nxv[r];

    // prefetch chunk c+1 (T14: full-chunk issue->use distance)
    {
      const int cc = (c < 127) ? (c + 1) : 127;
      PREFETCH(cc);
    }

    // ---- Attn = xc @ xb^T (frags double as A and B operands) ----
    f32x4 p = {0.f, 0.f, 0.f, 0.f};
    p = mfma16(xcr0, xbr0, p);
    p = mfma16(xcr1, xbr1, p);
    // mask tril, scale rows by -co[row], store P [i][j] (b128-readable as A-frag)
#pragma unroll
    for (int e = 0; e < 4; ++e) {
      const int i = l4 * 4 + e;
      const float v = (l15 <= i) ? p[e] * (-co_own[e]) : 0.f;
      lds_st<u16>(&ptw[i * 16 + l15], f2bf(v));
    }

    // ---- stage (-co15 * xb)^T for the W1-update A-operand ----
    {
      const float s = -co15;
#pragma unroll
      for (int r2 = 0; r2 < 4; ++r2) {
        u16x4 w;
#pragma unroll
        for (int i = 0; i < 4; ++i) w[i] = f2bf(bf2f(xv[r2 * 4 + i]) * s);
        lds_st<u16x4>(&xbTs[lane * 24 + r2 * 4], w);
      }
    }

    // ---- W1 master (C-layout f32) -> bf16 B-frags via LDS round trip ----
#pragma unroll
    for (int kb = 0; kb < 4; ++kb)
#pragma unroll
      for (int cb = 0; cb < 4; ++cb) {
        u16x4 w;
#pragma unroll
        for (int e = 0; e < 4; ++e) w[e] = f2bf(mW[kb][cb][e]);
        lds_st<u16x4>(&w1L[(cb * 16 + l15) * 72 + kb * 16 + l4 * 4], w);
      }
    dsfence();  // all w1L writes precede w1f reads (DS order only)
    bf16x8 w1f[4][2];
#pragma unroll
    for (int cb = 0; cb < 4; ++cb)
#pragma unroll
      for (int s = 0; s < 2; ++s)
        w1f[cb][s] = lds_ld<bf16x8>(&w1L[(cb * 16 + l15) * 72 + s * 32 + l4 * 8]);
    dsfence();

    // ---- Z1 = xb @ W1 + b1 ----
    f32x4 z[4];
#pragma unroll
    for (int cb = 0; cb < 4; ++cb) {
      f32x4 acc = {b1m[cb], b1m[cb], b1m[cb], b1m[cb]};
      acc = mfma16(xbr0, w1f[cb][0], acc);
      z[cb] = mfma16(xbr1, w1f[cb][1], acc);
    }
    // ---- xc @ W1 (independent of LN chain; overlaps it) ----
    f32x4 o2[4];
#pragma unroll
    for (int cb = 0; cb < 4; ++cb) {
      f32x4 acc = {0.f, 0.f, 0.f, 0.f};
      acc = mfma16(xcr0, w1f[cb][0], acc);
      o2[cb] = mfma16(xcr1, w1f[cb][1], acc);
    }

    // ---- LN backward: stats via shfl_xor 16-group reductions ----
    float xhat[4][4], gr[4][4];
#pragma unroll
    for (int e = 0; e < 4; ++e) {
      float s1 = z[0][e] + z[1][e] + z[2][e] + z[3][e];
      float s2 = z[0][e] * z[0][e] + z[1][e] * z[1][e] + z[2][e] * z[2][e] + z[3][e] * z[3][e];
      s1 = rsum16(s1);
      s2 = rsum16(s2);
      const float mu = s1 * 0.015625f;
      const float var = fmaxf(s2 * 0.015625f - mu * mu, 0.f);
      const float rstd = rsqrtf(var + 1e-6f);
      float gloc[4];
#pragma unroll
      for (int cb = 0; cb < 4; ++cb) {
        xhat[cb][e] = (z[cb][e] - mu) * rstd;
        gloc[cb] = (fmaf(lnw4[cb], xhat[cb][e], lnb4[cb]) - tgt[cb][e]) * lnw4[cb];
      }
      float gs = gloc[0] + gloc[1] + gloc[2] + gloc[3];
      float gx = gloc[0] * xhat[0][e] + gloc[1] * xhat[1][e] + gloc[2] * xhat[2][e] +
                 gloc[3] * xhat[3][e];
      gs = rsum16(gs);
      gx = rsum16(gx);
#pragma unroll
      for (int cb = 0; cb < 4; ++cb)
        gr[cb][e] = (64.f * gloc[cb] - gs - xhat[cb][e] * gx) * (rstd * 0.015625f);
    }

    // ---- column totals / prefix (for b1_bar, b1 update) ----
    float gtot[4], lower[4];
#pragma unroll
    for (int cb = 0; cb < 4; ++cb) {
      const float T = gr[cb][0] + gr[cb][1] + gr[cb][2] + gr[cb][3];
      const float t1 = __shfl_xor(T, 16, 64);
      const float t2 = __shfl_xor(T, 32, 64);
      const float t3 = __shfl_xor(t1, 32, 64);
      gtot[cb] = T + t1 + t2 + t3;
      lower[cb] = ((l4 & 1) ? t1 : 0.f) + ((l4 & 2) ? (t2 + t3) : 0.f);
    }

    // ---- grad^T to LDS -> B-frags (for P@grad and W1 update) ----
#pragma unroll
    for (int cb = 0; cb < 4; ++cb) {
      uint2 w = {pk2(gr[cb][0], gr[cb][1]), pk2(gr[cb][2], gr[cb][3])};
      lds_st<uint2>(&gTs[(cb * 16 + l15) * 24 + l4 * 4], w);
    }
    dsfence();  // gTs/xbTs/ptw writes precede frag reads
    bf16x8 gf[4];
    const bf16x8 zero8 = {};
#pragma unroll
    for (int cb = 0; cb < 4; ++cb) {
      bf16x8 v = lds_ld<bf16x8>(&gTs[(cb * 16 + l15) * 24 + (l4 & 1) * 8]);
      gf[cb] = klo ? v : zero8;
    }
    // P A-frag: row=l15, k=r=(l4&1)*8+e -> one b128 from ptw[l15][.] (K=32, upper 16 zero)
    bf16x8 ptf;
    {
      bf16x8 v = lds_ld<bf16x8>(&ptw[l15 * 16 + (l4 & 1) * 8]);
      ptf = klo ? v : zero8;
    }
    dsfence();

    // ---- Z1_bar = xc@W1 + (-co*P)@grad + b1_bar; LN fwd; output ----
#pragma unroll
    for (int cb = 0; cb < 4; ++cb) o2[cb] = mfma16(ptf, gf[cb], o2[cb]);
    float ov[4][4];
#pragma unroll
    for (int cb = 0; cb < 4; ++cb) {
      float pfx = lower[cb];
#pragma unroll
      for (int e = 0; e < 4; ++e) {
        pfx += gr[cb][e];
        ov[cb][e] = o2[cb][e] + fmaf(-co_own[e], pfx, b1m[cb]);
      }
    }
#pragma unroll
    for (int e = 0; e < 4; ++e) {
      float s1 = ov[0][e] + ov[1][e] + ov[2][e] + ov[3][e];
      float s2 = ov[0][e] * ov[0][e] + ov[1][e] * ov[1][e] + ov[2][e] * ov[2][e] +
                 ov[3][e] * ov[3][e];
      s1 = rsum16(s1);
      s2 = rsum16(s2);
      const float mu = s1 * 0.015625f;
      const float var = fmaxf(s2 * 0.015625f - mu * mu, 0.f);
      const float rstd = rsqrtf(var + 1e-6f);
      const size_t rowg = (size_t)(b * 2048 + c * 16 + l4 * 4 + e) * 2048 + h * 64;
#pragma unroll
      for (int cb = 0; cb < 4; ++cb) {
        const float y = xcC[cb][e] + fmaf(lnw4[cb], (ov[cb][e] - mu) * rstd, lnb4[cb]);
        XCW[rowg + cb * 16 + l15] = f2bf(y);
      }
    }

    // ---- W1 update: mW += (-co15*xb)^T @ grad  (16 MFMAs into the master) ----
    bf16x8 xbtf[4];
#pragma unroll
    for (int kb = 0; kb < 4; ++kb) {
      bf16x8 v = lds_ld<bf16x8>(&xbTs[(kb * 16 + l15) * 24 + (l4 & 1) * 8]);
      xbtf[kb] = klo ? v : zero8;
    }
    dsfence();
#pragma unroll
    for (int kb = 0; kb < 4; ++kb)
#pragma unroll
      for (int cb = 0; cb < 4; ++cb) mW[kb][cb] = mfma16(xbtf[kb], gf[cb], mW[kb][cb]);
    // b1 update
#pragma unroll
    for (int cb = 0; cb < 4; ++cb) b1m[cb] = fmaf(-co15, gtot[cb], b1m[cb]);
    dsfence();  // keep next iteration's LDS writes behind this iteration's reads
  }
#undef PREFETCH
}

// ---------- launcher ----------
extern "C" void kernel_launch(void* const* d_in, const int* in_sizes, int n_in, void* d_out,
                              int out_size, void* d_ws, size_t ws_size, hipStream_t stream) {
  const float* hs = (const float*)d_in[0];
  const float* Wq = (const float*)d_in[1];
  const float* Wk = (const float*)d_in[2];
  const float* Wv = (const float*)d_in[3];
  const float* Wo = (const float*)d_in[4];
  const float* ilr_w = (const float*)d_in[5];
  const float* ilr_b = (const float*)d_in[6];
  const float* lnw = (const float*)d_in[7];
  const float* lnb = (const float*)d_in[8];
  const float* W1 = (const float*)d_in[9];
  const float* b1 = (const float*)d_in[10];
  float* out = (float*)d_out;

  if (ws_size < 93847552u) return;  // diagnosable clean-fail instead of device fault
  char* ws = (char*)d_ws;
  u16* hsb = (u16*)(ws + 0);                 // 33.5 MB; reused as XCW after gemm<0>
  u16* WcatT = (u16*)(ws + 33554432);        // 25.7 MB; reused as WoT after gemm<0>
  u16* XCbf = (u16*)(ws + 59244544);         // 33.5 MB
  float* coeffb = (float*)(ws + 92798976);   // 1 MB
  u16* XCW = hsb;
  u16* WoT = (u16*)(ws + 33554432);
  u16* XBbf = (u16*)d_out;                       // d_out as scratch (dead before gemm<1>)
  u16* XAbf = (u16*)((char*)d_out + 33554432);

  conv_bf16<<<8192, 256, 0, stream>>>(hs, hsb);
  wt_conv<<<dim3(32, 32), 256, 0, stream>>>(Wq, WcatT, 2048, 2048);
  wt_conv<<<dim3(32, 32), 256, 0, stream>>>(Wk, WcatT + (size_t)2048 * 2048, 2048, 2048);
  wt_conv<<<dim3(32, 32), 256, 0, stream>>>(Wv, WcatT + (size_t)4096 * 2048, 2048, 2048);
  ilr_strip<<<1024, 256, 0, stream>>>(ilr_w, WcatT);

  gemm_bt<0><<<dim3(49, 64), 256, 0, stream>>>(hsb, WcatT, 8192, 6272, 2048, XCbf, XBbf, XAbf,
                                               coeffb, ilr_b, nullptr);
  wt_conv<<<dim3(32, 32), 256, 0, stream>>>(Wo, WoT, 2048, 2048);
  ttt_scan<<<128, 64, 0, stream>>>(XCbf, XBbf, XAbf, coeffb, lnw, lnb, W1, b1, XCW);
  gemm_bt<1><<<dim3(16, 64), 256, 0, stream>>>(XCW, WoT, 8192, 2048, 2048, nullptr, nullptr,
                                               nullptr, nullptr, nullptr, out);

  (void)in_sizes; (void)n_in; (void)out_size;
}

// Round 8
// 750.296 us; speedup vs baseline: 2.0158x; 1.0664x over previous
//
#include <hip/hip_runtime.h>
#include <hip/hip_bf16.h>

// ---------- types ----------
typedef __attribute__((ext_vector_type(8))) short bf16x8;   // 8 bf16 in 4 VGPRs
typedef __attribute__((ext_vector_type(4))) float f32x4;
typedef __attribute__((ext_vector_type(8))) unsigned short u16x8;
typedef __attribute__((ext_vector_type(4))) unsigned short u16x4;
typedef unsigned short u16;

#define AS1(p) ((__attribute__((address_space(1))) void*)(p))
#define AS3(p) ((__attribute__((address_space(3))) void*)(p))
#define GLL16(g, l) __builtin_amdgcn_global_load_lds(AS1(g), AS3(l), 16, 0, 0)

__device__ __forceinline__ u16 f2bf(float x) {
  return __builtin_bit_cast(u16, __float2bfloat16(x));
}
__device__ __forceinline__ float bf2f(u16 u) {
  return __builtin_bit_cast(float, ((unsigned)u) << 16);
}
__device__ __forceinline__ unsigned pk2(float a, float b) {
  return (unsigned)f2bf(a) | ((unsigned)f2bf(b) << 16);
}
__device__ __forceinline__ f32x4 mfma16(bf16x8 a, bf16x8 b, f32x4 c) {
  return __builtin_amdgcn_mfma_f32_16x16x32_bf16(a, b, c, 0, 0, 0);
}
// sum over each 16-lane row via DPP row_ror rotate-accumulate (pure VALU pipe).
// R5 exonerated DPP for the R4 NaN (shfl version failed identically; LDS aliasing
// was the culprit, fixed in R6). This moves 96 DS-pipe shuffles/chunk to VALU.
#define DPPADD(x, ctrl)                                                            \
  ((x) + __builtin_bit_cast(float, __builtin_amdgcn_update_dpp(                    \
             0, __builtin_bit_cast(int, (x)), (ctrl), 0xf, 0xf, true)))
__device__ __forceinline__ float rsum16(float x) {
  x = DPPADD(x, 0x128);  // row_ror:8
  x = DPPADD(x, 0x124);  // row_ror:4
  x = DPPADD(x, 0x122);  // row_ror:2
  x = DPPADD(x, 0x121);  // row_ror:1
  return x;
}
// DS-only scheduling fence: VALU/SALU/MFMA/VMEM may cross, DS ops may not.
__device__ __forceinline__ void dsfence() { __builtin_amdgcn_sched_barrier(0x7F); }
// aliasing-legal LDS store/load (memcpy is char-based: ordering is mandatory)
template <typename T>
__device__ __forceinline__ void lds_st(u16* p, T v) {
  __builtin_memcpy((void*)p, &v, sizeof(T));
}
template <typename T>
__device__ __forceinline__ T lds_ld(const u16* p) {
  T v;
  __builtin_memcpy(&v, (const void*)p, sizeof(T));
  return v;
}

// ---------- convert hs f32 -> bf16 (8 elems/thread) ----------
__global__ __launch_bounds__(256) void conv_bf16(const float* __restrict__ in,
                                                 u16* __restrict__ out) {
  size_t g = (size_t)blockIdx.x * 256 + threadIdx.x;
  const float4* p = reinterpret_cast<const float4*>(in) + g * 2;
  float4 a = p[0], b = p[1];
  u16x8 r;
  r[0] = f2bf(a.x); r[1] = f2bf(a.y); r[2] = f2bf(a.z); r[3] = f2bf(a.w);
  r[4] = f2bf(b.x); r[5] = f2bf(b.y); r[6] = f2bf(b.z); r[7] = f2bf(b.w);
  *reinterpret_cast<u16x8*>(out + g * 8) = r;
}

// ---------- transpose + convert: W[K][N] f32 -> Wt[N][K] bf16 ----------
__global__ __launch_bounds__(256) void wt_conv(const float* __restrict__ W,
                                               u16* __restrict__ Wt, int Kd, int N) {
  __shared__ float t[64][65];
  const int n0 = blockIdx.x * 64, k0 = blockIdx.y * 64;
  const int tx = threadIdx.x & 63, ty = threadIdx.x >> 6;
#pragma unroll
  for (int rr = 0; rr < 16; ++rr) {
    int r = rr * 4 + ty;
    t[r][tx] = W[(size_t)(k0 + r) * N + n0 + tx];
  }
  __syncthreads();
#pragma unroll
  for (int rr = 0; rr < 16; ++rr) {
    int r = rr * 4 + ty;
    Wt[(size_t)(n0 + r) * Kd + k0 + tx] = f2bf(t[tx][r]);
  }
}

// ---------- ilr_w strip into WcatT rows [6144,6272) ----------
__global__ __launch_bounds__(256) void ilr_strip(const float* __restrict__ ilr_w,
                                                 u16* __restrict__ WcatT) {
  int g = blockIdx.x * 256 + threadIdx.x;  // 128*2048
  int p = g >> 11, k = g & 2047;
  float v = (p < 32) ? ilr_w[k * 32 + p] : 0.f;
  WcatT[(size_t)(6144 + p) * 2048 + k] = f2bf(v);
}

// ---------- staging: 128x32 bf16 tile per matrix ----------
__device__ __forceinline__ void stage_pair(const u16* __restrict__ A, const u16* __restrict__ Bt,
                                           u16* As, u16* Bs, int Kd, int mT, int nT, int kt,
                                           int tid) {
#pragma unroll
  for (int r = 0; r < 2; ++r) {
    int e = r * 2048 + tid * 8;
    int row = e >> 5, kk = e & 31;
    GLL16(A + (size_t)(mT + row) * Kd + kt + kk, As + e);
    GLL16(Bt + (size_t)(nT + row) * Kd + kt + kk, Bs + e);
  }
}

// ---------- MFMA GEMM  C[M][N] = A[M][Kd] * Bt[N][Kd]^T ----------
template <int MODE>
__global__ __launch_bounds__(256) void gemm_bt(const u16* __restrict__ A,
                                               const u16* __restrict__ Bt, int M, int N, int Kd,
                                               u16* __restrict__ O0, u16* __restrict__ O1,
                                               u16* __restrict__ O2,
                                               float* __restrict__ coeffOut,
                                               const float* __restrict__ ilrb,
                                               float* __restrict__ Cout) {
  __shared__ __align__(16) u16 As[2][4096];
  __shared__ __align__(16) u16 Bs[2][4096];
  const int tid = threadIdx.x;
  const int lane = tid & 63;
  const int wid = tid >> 6;
  const int wr = wid >> 1, wc = wid & 1;
  const int l15 = lane & 15, l4 = lane >> 4;
  const int mT = blockIdx.y << 7, nT = blockIdx.x << 7;

  f32x4 acc[4][4];
#pragma unroll
  for (int m = 0; m < 4; ++m)
#pragma unroll
    for (int n = 0; n < 4; ++n) acc[m][n] = (f32x4){0.f, 0.f, 0.f, 0.f};

  stage_pair(A, Bt, &As[0][0], &Bs[0][0], Kd, mT, nT, 0, tid);
  const int nIter = Kd >> 5;
  const int aoff = (wr * 64 + l15) * 32 + l4 * 8;
  const int boff = (wc * 64 + l15) * 32 + l4 * 8;
#pragma unroll 1
  for (int it = 0; it < nIter; ++it) {
    const int cur = it & 1;
    __syncthreads();
    if (it + 1 < nIter)
      stage_pair(A, Bt, &As[cur ^ 1][0], &Bs[cur ^ 1][0], Kd, mT, nT, (it + 1) << 5, tid);
    bf16x8 av[4], bv[4];
#pragma unroll
    for (int x = 0; x < 4; ++x) {
      av[x] = *reinterpret_cast<const bf16x8*>(&As[cur][aoff + x * 512]);
      bv[x] = *reinterpret_cast<const bf16x8*>(&Bs[cur][boff + x * 512]);
    }
#pragma unroll
    for (int m = 0; m < 4; ++m)
#pragma unroll
      for (int n = 0; n < 4; ++n) acc[m][n] = mfma16(av[m], bv[n], acc[m][n]);
  }
#pragma unroll
  for (int m = 0; m < 4; ++m) {
#pragma unroll
    for (int n = 0; n < 4; ++n) {
      const int col = nT + wc * 64 + n * 16 + l15;
#pragma unroll
      for (int e = 0; e < 4; ++e) {
        const int row = mT + wr * 64 + m * 16 + l4 * 4 + e;
        float v = acc[m][n][e];
        if constexpr (MODE == 1) {
          Cout[(size_t)row * N + col] = v;
        } else {
          const int bb = row >> 11, lt = row & 2047;
          if (col < 6144) {
            const int mat = col >> 11;
            u16* base = (mat == 0) ? O0 : ((mat == 1) ? O1 : O2);
            const int hh = (col >> 6) & 31, dd = col & 63;
            base[(((size_t)(bb * 32 + hh)) * 2048 + lt) * 64 + dd] = f2bf(v);
          } else {
            const int h3 = col - 6144;
            if (h3 < 32) {
              const float x = v + ilrb[h3];
              const float sig = 1.f / (1.f + expf(-x));
              const int tok = lt & 15;
              coeffOut[((size_t)(bb * 32 + h3)) * 2048 + lt] =
                  sig * (1.f / (64.f * (float)(tok + 1)));
            }
          }
        }
      }
    }
  }
  (void)M;
}

// ---------- 1-wave-per-(b,h) TTT scan: no barriers, W1 in MFMA C-layout regs ----------
// lane: l15 = lane&15, l4 = lane>>4. C-layout: row = l4*4+e, col(tile cb) = cb*16+l15.
// A/B-frag: row/col = l15, k = l4*8+e (+32s). mW[kb][cb][e] = W1[kb*16+l4*4+e][cb*16+l15].
// LDS round-trips via memcpy + dsfence; row-16 reductions on the VALU pipe via DPP.
__global__ __launch_bounds__(64) void ttt_scan(
    const u16* __restrict__ XC, const u16* __restrict__ XB, const u16* __restrict__ XA,
    const float* __restrict__ coeff, const float* __restrict__ lnw_g,
    const float* __restrict__ lnb_g, const float* __restrict__ W1g,
    const float* __restrict__ b1g, u16* __restrict__ XCW) {
  const int bh = blockIdx.x;
  const int b = bh >> 5, h = bh & 31;
  const int lane = threadIdx.x & 63;
  const int l15 = lane & 15, l4 = lane >> 4;
  const bool klo = (l4 < 2);  // lanes whose frag k-slots (l4*8+e) are < 16

  const u16* xbb = XB + (size_t)bh * 131072;
  const u16* xcb = XC + (size_t)bh * 131072;
  const u16* xab = XA + (size_t)bh * 131072;
  const float* cob = coeff + (size_t)bh * 2048;

  float lnw4[4], lnb4[4], b1m[4];
#pragma unroll
  for (int cb = 0; cb < 4; ++cb) {
    lnw4[cb] = lnw_g[h * 64 + cb * 16 + l15];
    lnb4[cb] = lnb_g[h * 64 + cb * 16 + l15];
    b1m[cb] = b1g[h * 64 + cb * 16 + l15];
  }
  f32x4 mW[4][4];
#pragma unroll
  for (int kb = 0; kb < 4; ++kb)
#pragma unroll
    for (int cb = 0; cb < 4; ++cb)
#pragma unroll
      for (int e = 0; e < 4; ++e)
        mW[kb][cb][e] = W1g[(size_t)h * 4096 + (kb * 16 + l4 * 4 + e) * 64 + cb * 16 + l15];

  __shared__ __align__(16) u16 w1L[64 * 72];   // [col][k] W1^T bf16, stride 72
  __shared__ __align__(16) u16 xbTs[64 * 24];  // [col][r] (-co15*xb)^T bf16, stride 24
  __shared__ __align__(16) u16 gTs[64 * 24];   // [col][r] grad^T bf16, stride 24
  __shared__ __align__(16) u16 ptw[256];       // P [i][j] (masked, -co[i]-scaled)

  // ---- chunk-ahead prefetch state (frags + C-layout scalars + xv rows + coeff) ----
  uint4 nfb0, nfb1, nfc0, nfc1;
  float nco[4], nco15;
  u16 nxa[4][4], nxbC[4][4], nxcC[4][4], nxv[16];
  const int fo = l15 * 128 + l4 * 16;
#define PREFETCH(cc)                                                                 \
  do {                                                                               \
    const char* pb = (const char*)(xbb + (cc) * 1024);                               \
    const char* pc = (const char*)(xcb + (cc) * 1024);                               \
    nfb0 = *(const uint4*)(pb + fo); nfb1 = *(const uint4*)(pb + fo + 64);           \
    nfc0 = *(const uint4*)(pc + fo); nfc1 = *(const uint4*)(pc + fo + 64);           \
    const u16* xap_ = xab + (cc) * 1024;                                             \
    const u16* xbp_ = xbb + (cc) * 1024;                                             \
    const u16* xcp_ = xcb + (cc) * 1024;                                             \
    _Pragma("unroll") for (int cb = 0; cb < 4; ++cb)                                 \
        _Pragma("unroll") for (int e = 0; e < 4; ++e) {                              \
      const int idx = (l4 * 4 + e) * 64 + cb * 16 + l15;                             \
      nxa[cb][e] = xap_[idx];                                                        \
      nxbC[cb][e] = xbp_[idx];                                                       \
      nxcC[cb][e] = xcp_[idx];                                                       \
    }                                                                                \
    _Pragma("unroll") for (int r = 0; r < 16; ++r) nxv[r] = xbp_[r * 64 + lane];     \
    _Pragma("unroll") for (int e = 0; e < 4; ++e) nco[e] = cob[(cc) * 16 + l4 * 4 + e]; \
    nco15 = cob[(cc) * 16 + 15];                                                     \
  } while (0)

  PREFETCH(0);

#pragma unroll 1
  for (int c = 0; c < 128; ++c) {
    const bf16x8 xbr0 = __builtin_bit_cast(bf16x8, nfb0);
    const bf16x8 xbr1 = __builtin_bit_cast(bf16x8, nfb1);
    const bf16x8 xcr0 = __builtin_bit_cast(bf16x8, nfc0);
    const bf16x8 xcr1 = __builtin_bit_cast(bf16x8, nfc1);
    float co_own[4];
#pragma unroll
    for (int e = 0; e < 4; ++e) co_own[e] = nco[e];
    const float co15 = nco15;
    float tgt[4][4], xcC[4][4];
#pragma unroll
    for (int cb = 0; cb < 4; ++cb)
#pragma unroll
      for (int e = 0; e < 4; ++e) {
        tgt[cb][e] = bf2f(nxa[cb][e]) - bf2f(nxbC[cb][e]);
        xcC[cb][e] = bf2f(nxcC[cb][e]);
      }
    u16 xv[16];
#pragma unroll
    for (int r = 0; r < 16; ++r) xv[r] = nxv[r];

    // prefetch chunk c+1 (T14: full-chunk issue->use distance)
    {
      const int cc = (c < 127) ? (c + 1) : 127;
      PREFETCH(cc);
    }

    // ---- Attn = xc @ xb^T (frags double as A and B operands) ----
    f32x4 p = {0.f, 0.f, 0.f, 0.f};
    p = mfma16(xcr0, xbr0, p);
    p = mfma16(xcr1, xbr1, p);
    // mask tril, scale rows by -co[row], store P [i][j] (b128-readable as A-frag)
#pragma unroll
    for (int e = 0; e < 4; ++e) {
      const int i = l4 * 4 + e;
      const float v = (l15 <= i) ? p[e] * (-co_own[e]) : 0.f;
      lds_st<u16>(&ptw[i * 16 + l15], f2bf(v));
    }

    // ---- stage (-co15 * xb)^T for the W1-update A-operand ----
    {
      const float s = -co15;
#pragma unroll
      for (int r2 = 0; r2 < 4; ++r2) {
        u16x4 w;
#pragma unroll
        for (int i = 0; i < 4; ++i) w[i] = f2bf(bf2f(xv[r2 * 4 + i]) * s);
        lds_st<u16x4>(&xbTs[lane * 24 + r2 * 4], w);
      }
    }

    // ---- W1 master (C-layout f32) -> bf16 B-frags via LDS round trip ----
#pragma unroll
    for (int kb = 0; kb < 4; ++kb)
#pragma unroll
      for (int cb = 0; cb < 4; ++cb) {
        u16x4 w;
#pragma unroll
        for (int e = 0; e < 4; ++e) w[e] = f2bf(mW[kb][cb][e]);
        lds_st<u16x4>(&w1L[(cb * 16 + l15) * 72 + kb * 16 + l4 * 4], w);
      }
    dsfence();  // all w1L writes precede w1f reads (DS order only)
    bf16x8 w1f[4][2];
#pragma unroll
    for (int cb = 0; cb < 4; ++cb)
#pragma unroll
      for (int s = 0; s < 2; ++s)
        w1f[cb][s] = lds_ld<bf16x8>(&w1L[(cb * 16 + l15) * 72 + s * 32 + l4 * 8]);
    dsfence();

    // ---- Z1 = xb @ W1 + b1 ----
    f32x4 z[4];
#pragma unroll
    for (int cb = 0; cb < 4; ++cb) {
      f32x4 acc = {b1m[cb], b1m[cb], b1m[cb], b1m[cb]};
      acc = mfma16(xbr0, w1f[cb][0], acc);
      z[cb] = mfma16(xbr1, w1f[cb][1], acc);
    }
    // ---- xc @ W1 (independent of LN chain; overlaps it) ----
    f32x4 o2[4];
#pragma unroll
    for (int cb = 0; cb < 4; ++cb) {
      f32x4 acc = {0.f, 0.f, 0.f, 0.f};
      acc = mfma16(xcr0, w1f[cb][0], acc);
      o2[cb] = mfma16(xcr1, w1f[cb][1], acc);
    }

    // ---- LN backward: stats via DPP row-reductions (VALU pipe) ----
    float xhat[4][4], gr[4][4];
#pragma unroll
    for (int e = 0; e < 4; ++e) {
      float s1 = z[0][e] + z[1][e] + z[2][e] + z[3][e];
      float s2 = z[0][e] * z[0][e] + z[1][e] * z[1][e] + z[2][e] * z[2][e] + z[3][e] * z[3][e];
      s1 = rsum16(s1);
      s2 = rsum16(s2);
      const float mu = s1 * 0.015625f;
      const float var = fmaxf(s2 * 0.015625f - mu * mu, 0.f);
      const float rstd = rsqrtf(var + 1e-6f);
      float gloc[4];
#pragma unroll
      for (int cb = 0; cb < 4; ++cb) {
        xhat[cb][e] = (z[cb][e] - mu) * rstd;
        gloc[cb] = (fmaf(lnw4[cb], xhat[cb][e], lnb4[cb]) - tgt[cb][e]) * lnw4[cb];
      }
      float gs = gloc[0] + gloc[1] + gloc[2] + gloc[3];
      float gx = gloc[0] * xhat[0][e] + gloc[1] * xhat[1][e] + gloc[2] * xhat[2][e] +
                 gloc[3] * xhat[3][e];
      gs = rsum16(gs);
      gx = rsum16(gx);
#pragma unroll
      for (int cb = 0; cb < 4; ++cb)
        gr[cb][e] = (64.f * gloc[cb] - gs - xhat[cb][e] * gx) * (rstd * 0.015625f);
    }

    // ---- column totals / prefix (for b1_bar, b1 update) ----
    float gtot[4], lower[4];
#pragma unroll
    for (int cb = 0; cb < 4; ++cb) {
      const float T = gr[cb][0] + gr[cb][1] + gr[cb][2] + gr[cb][3];
      const float t1 = __shfl_xor(T, 16, 64);
      const float t2 = __shfl_xor(T, 32, 64);
      const float t3 = __shfl_xor(t1, 32, 64);
      gtot[cb] = T + t1 + t2 + t3;
      lower[cb] = ((l4 & 1) ? t1 : 0.f) + ((l4 & 2) ? (t2 + t3) : 0.f);
    }

    // ---- grad^T to LDS -> B-frags (for P@grad and W1 update) ----
#pragma unroll
    for (int cb = 0; cb < 4; ++cb) {
      uint2 w = {pk2(gr[cb][0], gr[cb][1]), pk2(gr[cb][2], gr[cb][3])};
      lds_st<uint2>(&gTs[(cb * 16 + l15) * 24 + l4 * 4], w);
    }
    dsfence();  // gTs/xbTs/ptw writes precede frag reads
    bf16x8 gf[4];
    const bf16x8 zero8 = {};
#pragma unroll
    for (int cb = 0; cb < 4; ++cb) {
      bf16x8 v = lds_ld<bf16x8>(&gTs[(cb * 16 + l15) * 24 + (l4 & 1) * 8]);
      gf[cb] = klo ? v : zero8;
    }
    // P A-frag: row=l15, k=r=(l4&1)*8+e -> one b128 from ptw[l15][.] (K=32, upper 16 zero)
    bf16x8 ptf;
    {
      bf16x8 v = lds_ld<bf16x8>(&ptw[l15 * 16 + (l4 & 1) * 8]);
      ptf = klo ? v : zero8;
    }
    dsfence();

    // ---- Z1_bar = xc@W1 + (-co*P)@grad + b1_bar; LN fwd; output ----
#pragma unroll
    for (int cb = 0; cb < 4; ++cb) o2[cb] = mfma16(ptf, gf[cb], o2[cb]);
    float ov[4][4];
#pragma unroll
    for (int cb = 0; cb < 4; ++cb) {
      float pfx = lower[cb];
#pragma unroll
      for (int e = 0; e < 4; ++e) {
        pfx += gr[cb][e];
        ov[cb][e] = o2[cb][e] + fmaf(-co_own[e], pfx, b1m[cb]);
      }
    }
#pragma unroll
    for (int e = 0; e < 4; ++e) {
      float s1 = ov[0][e] + ov[1][e] + ov[2][e] + ov[3][e];
      float s2 = ov[0][e] * ov[0][e] + ov[1][e] * ov[1][e] + ov[2][e] * ov[2][e] +
                 ov[3][e] * ov[3][e];
      s1 = rsum16(s1);
      s2 = rsum16(s2);
      const float mu = s1 * 0.015625f;
      const float var = fmaxf(s2 * 0.015625f - mu * mu, 0.f);
      const float rstd = rsqrtf(var + 1e-6f);
      const size_t rowg = (size_t)(b * 2048 + c * 16 + l4 * 4 + e) * 2048 + h * 64;
#pragma unroll
      for (int cb = 0; cb < 4; ++cb) {
        const float y = xcC[cb][e] + fmaf(lnw4[cb], (ov[cb][e] - mu) * rstd, lnb4[cb]);
        XCW[rowg + cb * 16 + l15] = f2bf(y);
      }
    }

    // ---- W1 update: mW += (-co15*xb)^T @ grad  (16 MFMAs into the master) ----
    bf16x8 xbtf[4];
#pragma unroll
    for (int kb = 0; kb < 4; ++kb) {
      bf16x8 v = lds_ld<bf16x8>(&xbTs[(kb * 16 + l15) * 24 + (l4 & 1) * 8]);
      xbtf[kb] = klo ? v : zero8;
    }
    dsfence();
#pragma unroll
    for (int kb = 0; kb < 4; ++kb)
#pragma unroll
      for (int cb = 0; cb < 4; ++cb) mW[kb][cb] = mfma16(xbtf[kb], gf[cb], mW[kb][cb]);
    // b1 update
#pragma unroll
    for (int cb = 0; cb < 4; ++cb) b1m[cb] = fmaf(-co15, gtot[cb], b1m[cb]);
    dsfence();  // keep next iteration's LDS writes behind this iteration's reads
  }
#undef PREFETCH
}

// ---------- launcher ----------
extern "C" void kernel_launch(void* const* d_in, const int* in_sizes, int n_in, void* d_out,
                              int out_size, void* d_ws, size_t ws_size, hipStream_t stream) {
  const float* hs = (const float*)d_in[0];
  const float* Wq = (const float*)d_in[1];
  const float* Wk = (const float*)d_in[2];
  const float* Wv = (const float*)d_in[3];
  const float* Wo = (const float*)d_in[4];
  const float* ilr_w = (const float*)d_in[5];
  const float* ilr_b = (const float*)d_in[6];
  const float* lnw = (const float*)d_in[7];
  const float* lnb = (const float*)d_in[8];
  const float* W1 = (const float*)d_in[9];
  const float* b1 = (const float*)d_in[10];
  float* out = (float*)d_out;

  if (ws_size < 93847552u) return;  // diagnosable clean-fail instead of device fault
  char* ws = (char*)d_ws;
  u16* hsb = (u16*)(ws + 0);                 // 33.5 MB; reused as XCW after gemm<0>
  u16* WcatT = (u16*)(ws + 33554432);        // 25.7 MB; reused as WoT after gemm<0>
  u16* XCbf = (u16*)(ws + 59244544);         // 33.5 MB
  float* coeffb = (float*)(ws + 92798976);   // 1 MB
  u16* XCW = hsb;
  u16* WoT = (u16*)(ws + 33554432);
  u16* XBbf = (u16*)d_out;                       // d_out as scratch (dead before gemm<1>)
  u16* XAbf = (u16*)((char*)d_out + 33554432);

  conv_bf16<<<8192, 256, 0, stream>>>(hs, hsb);
  wt_conv<<<dim3(32, 32), 256, 0, stream>>>(Wq, WcatT, 2048, 2048);
  wt_conv<<<dim3(32, 32), 256, 0, stream>>>(Wk, WcatT + (size_t)2048 * 2048, 2048, 2048);
  wt_conv<<<dim3(32, 32), 256, 0, stream>>>(Wv, WcatT + (size_t)4096 * 2048, 2048, 2048);
  ilr_strip<<<1024, 256, 0, stream>>>(ilr_w, WcatT);

  gemm_bt<0><<<dim3(49, 64), 256, 0, stream>>>(hsb, WcatT, 8192, 6272, 2048, XCbf, XBbf, XAbf,
                                               coeffb, ilr_b, nullptr);
  wt_conv<<<dim3(32, 32), 256, 0, stream>>>(Wo, WoT, 2048, 2048);
  ttt_scan<<<128, 64, 0, stream>>>(XCbf, XBbf, XAbf, coeffb, lnw, lnb, W1, b1, XCW);
  gemm_bt<1><<<dim3(16, 64), 256, 0, stream>>>(XCW, WoT, 8192, 2048, 2048, nullptr, nullptr,
                                               nullptr, nullptr, nullptr, out);

  (void)in_sizes; (void)n_in; (void)out_size;
}